// Round 3
// baseline (545.963 us; speedup 1.0000x reference)
//
#include <hip/hip_runtime.h>
#include <stdint.h>

// ---- problem constants ----
#define B_   4
#define L_   2048
#define DM   1024
#define DIN  2048
#define NH   32
#define HD   64
#define DSTATE 64
#define DCONV  7
#define CONV_DIM 2176            // DIN + 2*DSTATE
#define DPROJ 4288               // 2*DIN + 2*DSTATE + 2*NH
#define NPAD 4352                // DPROJ padded to 128 (= 17*256)
#define BL   8192                // B_*L_
#define EPS  1e-5f
#define QC   128                 // scan chunk length
#define NCH  16                  // chunks per sequence

typedef unsigned short u16;
typedef unsigned int   u32;
typedef __bf16 bf16x8 __attribute__((ext_vector_type(8)));
typedef float  f32x4  __attribute__((ext_vector_type(4)));

__device__ __forceinline__ float b2f(u32 b) { return __uint_as_float(b << 16); }
__device__ __forceinline__ u16 f2b(float f) {
    u32 u = __float_as_uint(f);
    u32 r = (u + 0x7fffu + ((u >> 16) & 1u)) >> 16;
    return (u16)r;
}
__device__ __forceinline__ void unpack8(uint4 v, float* f) {
    f[0] = b2f(v.x & 0xffffu); f[1] = b2f(v.x >> 16);
    f[2] = b2f(v.y & 0xffffu); f[3] = b2f(v.y >> 16);
    f[4] = b2f(v.z & 0xffffu); f[5] = b2f(v.z >> 16);
    f[6] = b2f(v.w & 0xffffu); f[7] = b2f(v.w >> 16);
}
__device__ __forceinline__ uint4 pack8(const float* f) {
    uint4 v;
    v.x = (u32)f2b(f[0]) | ((u32)f2b(f[1]) << 16);
    v.y = (u32)f2b(f[2]) | ((u32)f2b(f[3]) << 16);
    v.z = (u32)f2b(f[4]) | ((u32)f2b(f[5]) << 16);
    v.w = (u32)f2b(f[6]) | ((u32)f2b(f[7]) << 16);
    return v;
}
// skewed LDS index for transposed tiles: row-stride 136 u16 + 8-u16 skew per 8 rows.
__device__ __forceinline__ int xts(int p, int s) { return p * 136 + ((p >> 3) << 3) + s; }
// async global->LDS, 16B per lane; lds base must be wave-uniform (HW adds lane*16)
__device__ __forceinline__ void gload_lds16(const u16* g, u16* l) {
    __builtin_amdgcn_global_load_lds((const __attribute__((address_space(1))) void*)g,
                                     (__attribute__((address_space(3))) void*)l, 16, 0, 0);
}

// ---------- weight conversion ----------
__global__ __launch_bounds__(256) void k_cvt_win(const float* __restrict__ W, u16* __restrict__ Wb) {
    int idx = blockIdx.x * 256 + threadIdx.x;      // over NPAD*DM
    int n = idx >> 10;                              // DM = 1024
    float v = (n < DPROJ) ? W[(size_t)n * DM + (idx & 1023)] : 0.f;
    Wb[idx] = f2b(v);
}
__global__ __launch_bounds__(256) void k_cvt_wout(const float* __restrict__ W, u16* __restrict__ Wb) {
    int idx = blockIdx.x * 256 + threadIdx.x;      // over DM*DIN
    Wb[idx] = f2b(W[idx]);
}
__global__ __launch_bounds__(256) void k_cvt_fcd(const float* __restrict__ W, u16* __restrict__ Wb) {
    int idx = blockIdx.x * 256 + threadIdx.x;      // over NH*DIN
    Wb[idx] = f2b(W[idx]);
}

// ---------- layernorm -> bf16 ----------
__global__ __launch_bounds__(256) void k_ln(const float* __restrict__ x, const float* __restrict__ g,
                                            const float* __restrict__ be, u16* __restrict__ u) {
    int row = blockIdx.x, tid = threadIdx.x;
    const float4* xr = (const float4*)(x + (size_t)row * DM);
    float4 v = xr[tid];
    float s1 = v.x + v.y + v.z + v.w;
    float s2 = v.x * v.x + v.y * v.y + v.z * v.z + v.w * v.w;
    for (int o = 32; o; o >>= 1) { s1 += __shfl_down(s1, o); s2 += __shfl_down(s2, o); }
    __shared__ float ls1[4], ls2[4];
    int w = tid >> 6;
    if ((tid & 63) == 0) { ls1[w] = s1; ls2[w] = s2; }
    __syncthreads();
    float t1 = ls1[0] + ls1[1] + ls1[2] + ls1[3];
    float t2 = ls2[0] + ls2[1] + ls2[2] + ls2[3];
    float mu = t1 * (1.f / DM);
    float var = t2 * (1.f / DM) - mu * mu;
    float rs = rsqrtf(var + EPS);
    float4 gv = ((const float4*)g)[tid];
    float4 bv = ((const float4*)be)[tid];
    float o0 = (v.x - mu) * rs * gv.x + bv.x;
    float o1 = (v.y - mu) * rs * gv.y + bv.y;
    float o2 = (v.z - mu) * rs * gv.z + bv.z;
    float o3 = (v.w - mu) * rs * gv.w + bv.w;
    uint2 p;
    p.x = (u32)f2b(o0) | ((u32)f2b(o1) << 16);
    p.y = (u32)f2b(o2) | ((u32)f2b(o3) << 16);
    ((uint2*)(u + (size_t)row * DM))[tid] = p;
}

// ======================================================================
// 256x256-tile bf16 GEMM, m201-style 8-phase schedule. C[m,n] = sum_k A[m,k]*B[n,k].
// BK=64 split in two K-half slabs of 256 rows x 32 cols (16 KB each).
// LDS = 2(dbuf, per-K-tile parity) x 2(k-half) x {A,B} x 16 KB = 128 KiB.
// Iteration i covers K-tiles t=2i (dbuf0) and t+1 (dbuf1), 8 phases:
//   phase = (tile, k-half, m-subhalf); per phase: {4 or 8 ds_read_b128,
//   stage ONE 16KB slab via 2 x global_load_lds(16B), [vmcnt(4) at p2/p6],
//   s_barrier, lgkmcnt(0), sched_barrier, setprio(1), 16 MFMA, setprio(0),
//   s_barrier}.  Stage->use distance = 6 phases; vmcnt never drains to 0 in
//   the main loop.  Stage schedule (steady iter, t=2i):
//     p1:A(t+1,k1)  p2:B(t+1,k1)+vm4  p3:A(t+2,k0)  p4:B(t+2,k0)
//     p5:A(t+2,k1)  p6:B(t+2,k1)+vm4  p7:A(t+3,k0)  p8:B(t+3,k0)
//   (every slab write is >=1 barrier after its last read; every read is
//    covered by the preceding vmcnt(4) -- verified slab-by-slab.)
// Swizzle: slab row r holds global chunk c^((r>>1)&3) at chunk c (16B chunks,
// 4/row); gload source pre-swizzled, ds_read applies same XOR -> 0 conflicts.
// Grid: 1-D 544 blocks, bijective XCD-chunked swizzle (544 = 8*68), column-
// chunked decode so each XCD's ~2 B-panels stay L2-resident.
// Requires M%256==0, N%256==0, K%128==0, K>=256.
// ======================================================================
#define G3_DSA(d, kh, ms)                                                        \
  { _Pragma("unroll")                                                            \
    for (int mi = 0; mi < 4; mi++)                                               \
      af_[mi] = *(const bf16x8*)&Asl[d][kh][a_rd + (ms) * 2048 + mi * 512]; }
#define G3_DSB(d, kh)                                                            \
  { _Pragma("unroll")                                                            \
    for (int nj = 0; nj < 4; nj++)                                               \
      bf_[nj] = *(const bf16x8*)&Bsl[d][kh][b_rd + nj * 512]; }
#define G3_STA(d, kh, tau)                                                       \
  { const size_t ko = (size_t)((tau) * 64 + (kh) * 32);                          \
    gload_lds16(Ag + a_src + ko, &Asl[d][kh][st_l]);                             \
    gload_lds16(Ag + a_src + srowK + ko, &Asl[d][kh][st_l + 512]); }
#define G3_STB(d, kh, tau)                                                       \
  { const size_t ko = (size_t)((tau) * 64 + (kh) * 32);                          \
    gload_lds16(Bg + b_src + ko, &Bsl[d][kh][st_l]);                             \
    gload_lds16(Bg + b_src + srowK + ko, &Bsl[d][kh][st_l + 512]); }
#define G3_MM(ms)                                                                \
  { __builtin_amdgcn_s_barrier();                                                \
    asm volatile("s_waitcnt lgkmcnt(0)" ::: "memory");                           \
    __builtin_amdgcn_sched_barrier(0);                                           \
    __builtin_amdgcn_s_setprio(1);                                               \
    _Pragma("unroll")                                                            \
    for (int mi = 0; mi < 4; mi++)                                               \
      _Pragma("unroll")                                                          \
      for (int nj = 0; nj < 4; nj++)                                             \
        acc[ms][mi][nj] = __builtin_amdgcn_mfma_f32_16x16x32_bf16(af_[mi], bf_[nj], acc[ms][mi][nj], 0, 0, 0); \
    __builtin_amdgcn_s_setprio(0);                                               \
    asm volatile("" ::: "memory");                                               \
    __builtin_amdgcn_s_barrier(); }
#define G3_VM4 asm volatile("s_waitcnt vmcnt(4)" ::: "memory");
#define G3_VM0 asm volatile("s_waitcnt vmcnt(0)" ::: "memory");

__global__ __launch_bounds__(512, 2) void k_gemm256(const u16* __restrict__ Ag, const u16* __restrict__ Bg,
                                                    int K, u16* __restrict__ obf, int ldo) {
    __shared__ __align__(16) u16 Asl[2][2][8192];   // [dbuf][khalf][256 rows x 32 cols]
    __shared__ __align__(16) u16 Bsl[2][2][8192];
    const int tid = threadIdx.x;
    const int w = tid >> 6, lane = tid & 63, lr = lane & 15, lq = lane >> 4;
    const int wm = w >> 2, wn = w & 3;                    // 2 (M) x 4 (N) waves
    // bijective XCD-chunked swizzle: 544 blocks = 8 XCDs x 68; column-chunked decode
    const int bid = blockIdx.x;
    const int swz = (bid & 7) * 68 + (bid >> 3);
    const int bx = swz >> 5, by = swz & 31;               // bx: N-block (0..16), by: M-block (0..31)
    const int m0 = by * 256, n0 = bx * 256;
    // staging: lane -> row lane>>2 (16 rows/gload), chunk lane&3, src pre-swizzled
    const int sr = lane >> 2;
    const int sc = (lane & 3) ^ ((lane >> 3) & 3);
    const size_t a_src = (size_t)(m0 + w * 32 + sr) * K + sc * 8;
    const size_t b_src = (size_t)(n0 + w * 32 + sr) * K + sc * 8;
    const size_t srowK = (size_t)16 * K;
    const int st_l = w * 1024;                            // wave-uniform LDS dst (u16)
    // ds_read addressing (swizzled chunk)
    const int swc = (lq ^ ((lr >> 1) & 3)) << 3;
    const int a_rd = (wm * 128 + lr) * 32 + swc;
    const int b_rd = (wn * 64 + lr) * 32 + swc;

    f32x4 acc[2][4][4];
    #pragma unroll
    for (int s = 0; s < 2; s++)
        #pragma unroll
        for (int i = 0; i < 4; i++)
            #pragma unroll
            for (int j = 0; j < 4; j++) acc[s][i][j] = (f32x4){0.f, 0.f, 0.f, 0.f};

    bf16x8 af_[4], bf_[4];

    // prologue: tiles 0 (both k-halves) + tile 1 k0 = 6 slabs (12 gloads/wave)
    G3_STA(0, 0, 0); G3_STB(0, 0, 0);
    G3_STA(0, 1, 0); G3_STB(0, 1, 0);
    G3_STA(1, 0, 1); G3_STB(1, 0, 1);
    G3_VM0;
    __builtin_amdgcn_s_barrier();

    const int NI = K >> 7;                                // iterations (2 K-tiles each)
    for (int i = 0; i < NI - 1; ++i) {
        const int t = 2 * i;
        G3_DSB(0, 0) G3_DSA(0, 0, 0) G3_STA(1, 1, t + 1);          G3_MM(0)   // p1
        G3_DSA(0, 0, 1) G3_STB(1, 1, t + 1); G3_VM4;               G3_MM(1)   // p2
        G3_DSB(0, 1) G3_DSA(0, 1, 0) G3_STA(0, 0, t + 2);          G3_MM(0)   // p3
        G3_DSA(0, 1, 1) G3_STB(0, 0, t + 2);                       G3_MM(1)   // p4
        G3_DSB(1, 0) G3_DSA(1, 0, 0) G3_STA(0, 1, t + 2);          G3_MM(0)   // p5
        G3_DSA(1, 0, 1) G3_STB(0, 1, t + 2); G3_VM4;               G3_MM(1)   // p6
        G3_DSB(1, 1) G3_DSA(1, 1, 0) G3_STA(1, 0, t + 3);          G3_MM(0)   // p7
        G3_DSA(1, 1, 1) G3_STB(1, 0, t + 3);                       G3_MM(1)   // p8
    }
    {   // last iteration: stage only tile (t+1) k1; drain with vmcnt(0) at p6
        const int t = 2 * (NI - 1);
        G3_DSB(0, 0) G3_DSA(0, 0, 0) G3_STA(1, 1, t + 1);          G3_MM(0)
        G3_DSA(0, 0, 1) G3_STB(1, 1, t + 1); G3_VM4;               G3_MM(1)
        G3_DSB(0, 1) G3_DSA(0, 1, 0)                               G3_MM(0)
        G3_DSA(0, 1, 1)                                            G3_MM(1)
        G3_DSB(1, 0) G3_DSA(1, 0, 0)                               G3_MM(0)
        G3_DSA(1, 0, 1) G3_VM0;                                    G3_MM(1)
        G3_DSB(1, 1) G3_DSA(1, 1, 0)                               G3_MM(0)
        G3_DSA(1, 1, 1)                                            G3_MM(1)
    }

    #pragma unroll
    for (int ms = 0; ms < 2; ms++)
        #pragma unroll
        for (int mi = 0; mi < 4; mi++)
            #pragma unroll
            for (int nj = 0; nj < 4; nj++)
                #pragma unroll
                for (int rr = 0; rr < 4; rr++) {
                    int m = m0 + wm * 128 + ms * 64 + mi * 16 + lq * 4 + rr;
                    int n = n0 + wn * 64 + nj * 16 + lr;
                    obf[(size_t)m * ldo + n] = f2b(acc[ms][mi][nj][rr]);
                }
}

// ---------- bf16 MFMA GEMM, C[m,n] = sum_k A[m,k]*B[n,k]  (B^T layout) ----------
__global__ __launch_bounds__(256) void k_gemm_bt(const u16* __restrict__ A, const u16* __restrict__ Bw,
                                                 int M, int N, int K, int out_bf16,
                                                 u16* __restrict__ obf, int ldo,
                                                 float* __restrict__ ofp, const float* __restrict__ res) {
    __shared__ __align__(16) u16 As[128 * 64];
    __shared__ __align__(16) u16 Bs[128 * 64];
    int tid = threadIdx.x;
    int m0 = blockIdx.y * 128, n0 = blockIdx.x * 128;
    int w = tid >> 6, lane = tid & 63;
    int wm = (w >> 1) * 64, wn = (w & 1) * 64;
    int lr = lane & 15, lq = lane >> 4;

    f32x4 acc[4][4];
    #pragma unroll
    for (int i = 0; i < 4; i++)
        #pragma unroll
        for (int j = 0; j < 4; j++) acc[i][j] = (f32x4){0.f, 0.f, 0.f, 0.f};

    for (int kt = 0; kt < K; kt += 64) {
        #pragma unroll
        for (int it = 0; it < 4; it++) {
            int s_idx = it * 256 + tid;
            int row = s_idx >> 3;
            int kcg = (s_idx & 7) ^ (row & 7);            // swizzled source chunk
            u16* lbase_a = &As[(it * 256 + w * 64) * 8];  // wave-uniform
            u16* lbase_b = &Bs[(it * 256 + w * 64) * 8];
            gload_lds16(A + (size_t)(m0 + row) * K + kt + kcg * 8, lbase_a);
            gload_lds16(Bw + (size_t)(n0 + row) * K + kt + kcg * 8, lbase_b);
        }
        __syncthreads();
        #pragma unroll
        for (int kk = 0; kk < 2; kk++) {
            bf16x8 af[4], bfr[4];
            #pragma unroll
            for (int i = 0; i < 4; i++) {
                int row = wm + 16 * i + lr;
                af[i] = *(const bf16x8*)&As[row * 64 + (((kk * 4 + lq)) ^ (row & 7)) * 8];
            }
            #pragma unroll
            for (int j = 0; j < 4; j++) {
                int row = wn + 16 * j + lr;
                bfr[j] = *(const bf16x8*)&Bs[row * 64 + (((kk * 4 + lq)) ^ (row & 7)) * 8];
            }
            #pragma unroll
            for (int i = 0; i < 4; i++)
                #pragma unroll
                for (int j = 0; j < 4; j++)
                    acc[i][j] = __builtin_amdgcn_mfma_f32_16x16x32_bf16(af[i], bfr[j], acc[i][j], 0, 0, 0);
        }
        __syncthreads();
    }
    #pragma unroll
    for (int i = 0; i < 4; i++) {
        #pragma unroll
        for (int j = 0; j < 4; j++) {
            #pragma unroll
            for (int rr = 0; rr < 4; rr++) {
                int m = m0 + wm + 16 * i + lq * 4 + rr;
                int n = n0 + wn + 16 * j + lr;
                float v = acc[i][j][rr];
                if (out_bf16) obf[(size_t)m * ldo + n] = f2b(v);
                else          ofp[(size_t)m * ldo + n] = v + res[(size_t)m * ldo + n];
            }
        }
    }
}

// ---------- D-projection GEMM: Dd[m][h] = dot(xs[m,:], fc_D_w[h,:]) + Dv[h] ----------
__global__ __launch_bounds__(256) void k_dproj(const u16* __restrict__ xs, const u16* __restrict__ fcb,
                                               const float* __restrict__ Dv, float* __restrict__ Dd) {
    __shared__ __align__(16) u16 As[32 * 72];
    __shared__ __align__(16) u16 Bs[32 * 72];
    int tid = threadIdx.x;
    int m0 = blockIdx.x * 32;
    int w = tid >> 6, lane = tid & 63, lr = lane & 15, lq = lane >> 4;
    int mt = (w & 1) * 16, nt = (w >> 1) * 16;
    int r = tid >> 3, kc = tid & 7;
    f32x4 acc = (f32x4){0.f, 0.f, 0.f, 0.f};
    for (int kt = 0; kt < DIN; kt += 64) {
        *(uint4*)&As[r * 72 + kc * 8] = *(const uint4*)(xs + (size_t)(m0 + r) * DIN + kt + kc * 8);
        *(uint4*)&Bs[r * 72 + kc * 8] = *(const uint4*)(fcb + (size_t)r * DIN + kt + kc * 8);
        __syncthreads();
        #pragma unroll
        for (int ks = 0; ks < 2; ks++) {
            bf16x8 a = *(const bf16x8*)&As[(mt + lr) * 72 + ks * 32 + lq * 8];
            bf16x8 b = *(const bf16x8*)&Bs[(nt + lr) * 72 + ks * 32 + lq * 8];
            acc = __builtin_amdgcn_mfma_f32_16x16x32_bf16(a, b, acc, 0, 0, 0);
        }
        __syncthreads();
    }
    #pragma unroll
    for (int rr = 0; rr < 4; rr++) {
        int m = m0 + mt + lq * 4 + rr;
        int n = nt + lr;
        Dd[(size_t)m * 32 + n] = acc[rr] + Dv[n];
    }
}

// ---------- depthwise conv7 (same-pad) + bias + SiLU, split xs / BC(bf16) ----------
__global__ __launch_bounds__(256) void k_conv(const u16* __restrict__ zx, const float* __restrict__ cw,
                                              const float* __restrict__ cb, u16* __restrict__ xs,
                                              u16* __restrict__ BCb) {
    __shared__ u16 sh[262 * 64];
    int c0 = blockIdx.x * 64, t0 = blockIdx.y * 256, b = blockIdx.z;
    int tid = threadIdx.x;
    int c = tid & 63, tg = tid >> 6;
    for (int it = 0; it < 66; it++) {
        int r = it * 4 + tg;
        if (r < 262) {
            int t = t0 + r - 3;
            u16 v = 0;
            if (t >= 0 && t < L_) v = zx[(size_t)(b * L_ + t) * NPAD + DIN + c0 + c];
            sh[r * 64 + c] = v;
        }
    }
    float wgt[7];
    #pragma unroll
    for (int k = 0; k < 7; k++) wgt[k] = cw[(c0 + c) * 7 + k];
    float bias = cb[c0 + c];
    __syncthreads();
    int cg = c0 + c;
    for (int tt = 0; tt < 64; tt++) {
        int tl = tt * 4 + tg;
        float a = bias;
        #pragma unroll
        for (int k = 0; k < 7; k++) a += b2f(sh[(tl + k) * 64 + c]) * wgt[k];
        float v = a / (1.f + __expf(-a));   // silu
        size_t row = (size_t)b * L_ + (t0 + tl);
        if (cg < DIN) xs[row * DIN + cg] = f2b(v);
        else          BCb[row * 128 + (cg - DIN)] = f2b(v);   // B at [0,64), C at [64,128), bf16
    }
}

// ======================================================================
// Chunked SSD scan (intra-chunk + chunk-state + inline dt): block = (dir,b,h,chunk).
// ======================================================================
__global__ __launch_bounds__(256) void k_chunk(const u16* __restrict__ xs, const u16* __restrict__ BCb,
                                               const u16* __restrict__ zx, const float* __restrict__ dt_bias,
                                               const float* __restrict__ A_log, u16* __restrict__ y0,
                                               u16* __restrict__ y1, float* __restrict__ wout,
                                               float* __restrict__ decay, u16* __restrict__ scb) {
    __shared__ __align__(16) u16 ab[18432];      // Cs [0,9216) stride 72, Bs [9216,18432); S overlays (skewed 136)
    __shared__ __align__(16) u16 XT[8768];       // X^T [p][s] skewed
    __shared__ __align__(16) u16 BT[8768];       // B^T [n][s] skewed
    __shared__ __align__(16) float dts_s[128];
    __shared__ __align__(16) float lda_s[128];
    __shared__ __align__(16) float wend[128];
    __shared__ __align__(16) double cumd[128];

    const int blk = blockIdx.x;
    const int c = blk & 15, dbh = blk >> 4;
    const int h = dbh & 31, b = (dbh >> 5) & 3, dir = dbh >> 7;
    const int tid = threadIdx.x, w = tid >> 6, lane = tid & 63, lr = lane & 15, lq = lane >> 4;
    const int s0 = c * QC;
    u16* yo = dir ? y1 : y0;

    if (tid < 128) {   // inline dt2 / log-dA
        int s = s0 + tid;
        int t = dir ? (L_ - 1 - s) : s;
        float draw = b2f(zx[(size_t)(b * L_ + t) * NPAD + (DIN + CONV_DIM) + dir * 32 + h]);
        float xb = draw + dt_bias[h];
        float dt2 = (xb > 20.f) ? xb : log1pf(__expf(xb));
        dts_s[tid] = dt2;
        lda_s[tid] = -__expf(A_log[h]) * dt2;
    }
    {   // stage Cs, Bs (bf16 row-major), BT, XT (transposed, skewed)
        int sl0 = tid >> 3, ng = (tid & 7) * 8;
        #pragma unroll
        for (int it = 0; it < 4; it++) {
            int sl = sl0 + it * 32;
            int s = s0 + sl;
            int t = dir ? (L_ - 1 - s) : s;
            size_t row = (size_t)b * L_ + t;
            const u16* bcr = BCb + row * 128;
            uint4 cv = *(const uint4*)(bcr + 64 + ng);
            *(uint4*)&ab[sl * 72 + ng] = cv;
            uint4 pb = *(const uint4*)(bcr + ng);
            *(uint4*)&ab[9216 + sl * 72 + ng] = pb;
            u16 bh[8] = {(u16)(pb.x & 0xffffu), (u16)(pb.x >> 16), (u16)(pb.y & 0xffffu), (u16)(pb.y >> 16),
                         (u16)(pb.z & 0xffffu), (u16)(pb.z >> 16), (u16)(pb.w & 0xffffu), (u16)(pb.w >> 16)};
            #pragma unroll
            for (int i = 0; i < 8; i++) BT[(ng + i) * 136 + ng + sl] = bh[i];   // skew = ng
            uint4 xv = *(const uint4*)(xs + row * DIN + h * 64 + ng);
            u16 xh[8] = {(u16)(xv.x & 0xffffu), (u16)(xv.x >> 16), (u16)(xv.y & 0xffffu), (u16)(xv.y >> 16),
                         (u16)(xv.z & 0xffffu), (u16)(xv.z >> 16), (u16)(xv.w & 0xffffu), (u16)(xv.w >> 16)};
            #pragma unroll
            for (int i = 0; i < 8; i++) XT[(ng + i) * 136 + ng + sl] = xh[i];   // skew = ng
        }
    }
    __syncthreads();
    if (w == 0) {   // double-precision inclusive prefix of log-dA (wave 0)
        double v0 = (double)lda_s[lane];
        double v1 = (double)lda_s[64 + lane];
        #pragma unroll
        for (int o = 1; o < 64; o <<= 1) {
            double t0 = __shfl_up(v0, o);
            double t1 = __shfl_up(v1, o);
            if (lane >= o) { v0 += t0; v1 += t1; }
        }
        double tot0 = __shfl(v0, 63);
        cumd[lane] = v0;
        cumd[64 + lane] = tot0 + v1;
    }
    // G = C * B^T  (wave w owns t-rows [w*32, w*32+32))
    bf16x8 af[2][2];
    #pragma unroll
    for (int ti = 0; ti < 2; ti++)
        #pragma unroll
        for (int ks = 0; ks < 2; ks++)
            af[ti][ks] = *(const bf16x8*)&ab[(w * 32 + ti * 16 + lr) * 72 + ks * 32 + lq * 8];
    f32x4 accg[2][8];
    #pragma unroll
    for (int ti = 0; ti < 2; ti++)
        #pragma unroll
        for (int si = 0; si < 8; si++) accg[ti][si] = (f32x4){0.f, 0.f, 0.f, 0.f};
    #pragma unroll
    for (int si = 0; si < 8; si++)
        #pragma unroll
        for (int ks = 0; ks < 2; ks++) {
            bf16x8 bf = *(const bf16x8*)&ab[9216 + (si * 16 + lr) * 72 + ks * 32 + lq * 8];
            accg[0][si] = __builtin_amdgcn_mfma_f32_16x16x32_bf16(af[0][ks], bf, accg[0][si], 0, 0, 0);
            accg[1][si] = __builtin_amdgcn_mfma_f32_16x16x32_bf16(af[1][ks], bf, accg[1][si], 0, 0, 0);
        }
    __syncthreads();   // all G frag reads done; cumd ready
    // wend[s] = exp(cum[127]-cum[s])*dt[s]  (for chunk-state); visible after next barrier
    if (tid < 128) wend[tid] = __expf((float)(cumd[127] - cumd[tid])) * dts_s[tid];
    // S = M .* G  -> overlay into ab (skewed stride 136)
    {
        double cumt_d[8];
        #pragma unroll
        for (int ti = 0; ti < 2; ti++)
            #pragma unroll
            for (int r = 0; r < 4; r++) cumt_d[ti * 4 + r] = cumd[w * 32 + ti * 16 + lq * 4 + r];
        double cums_d[8]; float dts_l[8];
        #pragma unroll
        for (int si = 0; si < 8; si++) { cums_d[si] = cumd[si * 16 + lr]; dts_l[si] = dts_s[si * 16 + lr]; }
        #pragma unroll
        for (int ti = 0; ti < 2; ti++)
            #pragma unroll
            for (int si = 0; si < 8; si++)
                #pragma unroll
                for (int r = 0; r < 4; r++) {
                    int t_l = w * 32 + ti * 16 + lq * 4 + r;
                    int s_l = si * 16 + lr;
                    float v = 0.f;
                    if (s_l <= t_l)
                        v = __expf((float)(cumt_d[ti * 4 + r] - cums_d[si])) * dts_l[si] * accg[ti][si][r];
                    ab[xts(t_l, s_l)] = f2b(v);
                }
    }
    __syncthreads();
    // Y_intra = S * X^T
    f32x4 acc[2][4];
    #pragma unroll
    for (int ti = 0; ti < 2; ti++)
        #pragma unroll
        for (int pj = 0; pj < 4; pj++) acc[ti][pj] = (f32x4){0.f, 0.f, 0.f, 0.f};
    #pragma unroll
    for (int ks = 0; ks < 4; ks++) {
        bf16x8 a0 = *(const bf16x8*)&ab[xts(w * 32 + lr, ks * 32 + lq * 8)];
        bf16x8 a1 = *(const bf16x8*)&ab[xts(w * 32 + 16 + lr, ks * 32 + lq * 8)];
        #pragma unroll
        for (int pj = 0; pj < 4; pj++) {
            bf16x8 bf = *(const bf16x8*)&XT[xts(pj * 16 + lr, ks * 32 + lq * 8)];
            acc[0][pj] = __builtin_amdgcn_mfma_f32_16x16x32_bf16(a0, bf, acc[0][pj], 0, 0, 0);
            acc[1][pj] = __builtin_amdgcn_mfma_f32_16x16x32_bf16(a1, bf, acc[1][pj], 0, 0, 0);
        }
    }
    #pragma unroll
    for (int ti = 0; ti < 2; ti++)
        #pragma unroll
        for (int pj = 0; pj < 4; pj++)
            #pragma unroll
            for (int r = 0; r < 4; r++) {
                int t_l = w * 32 + ti * 16 + lq * 4 + r;
                int s = s0 + t_l;
                int t = dir ? (L_ - 1 - s) : s;
                yo[((size_t)b * L_ + t) * DIN + h * 64 + pj * 16 + lr] = f2b(acc[ti][pj][r]);
            }
    // chunk state S_c[p][n] = sum_s wend[s]*x[s][p]*B[s][n]
    f32x4 accs[4];
    #pragma unroll
    for (int nj = 0; nj < 4; nj++) accs[nj] = (f32x4){0.f, 0.f, 0.f, 0.f};
    #pragma unroll
    for (int ks = 0; ks < 4; ks++) {
        uint4 xv = *(const uint4*)&XT[xts(w * 16 + lr, ks * 32 + lq * 8)];
        float xf[8]; unpack8(xv, xf);
        float4 w0 = *(const float4*)&wend[ks * 32 + lq * 8];
        float4 w1 = *(const float4*)&wend[ks * 32 + lq * 8 + 4];
        float fs[8] = {xf[0]*w0.x, xf[1]*w0.y, xf[2]*w0.z, xf[3]*w0.w,
                       xf[4]*w1.x, xf[5]*w1.y, xf[6]*w1.z, xf[7]*w1.w};
        bf16x8 a = __builtin_bit_cast(bf16x8, pack8(fs));
        #pragma unroll
        for (int nj = 0; nj < 4; nj++) {
            bf16x8 bb = *(const bf16x8*)&BT[xts(nj * 16 + lr, ks * 32 + lq * 8)];
            accs[nj] = __builtin_amdgcn_mfma_f32_16x16x32_bf16(a, bb, accs[nj], 0, 0, 0);
        }
    }
    #pragma unroll
    for (int nj = 0; nj < 4; nj++)
        #pragma unroll
        for (int r = 0; r < 4; r++) {
            int p = w * 16 + lq * 4 + r, n = nj * 16 + lr;
            scb[(size_t)blk * 4096 + p * 64 + n] = f2b(accs[nj][r]);
        }
    if (tid < 128) wout[dbh * 2048 + s0 + tid] = __expf((float)cumd[tid]);
    if (tid == 0)  decay[blk] = __expf((float)cumd[127]);
}

// ---------- h-state scan (barrier-free): rewrites scb slots in place with h_in per chunk ----------
// thread owns 16 (p,n) elements; the recurrence h = decay*h + S_c is elementwise.
__global__ __launch_bounds__(256) void k_hscan(const float* __restrict__ decay, u16* __restrict__ scb) {
    int dbh = blockIdx.x, tid = threadIdx.x;
    u16* base = scb + (size_t)dbh * 16 * 4096 + tid * 16;
    float hcur[16];
    #pragma unroll
    for (int i = 0; i < 16; i++) hcur[i] = 0.f;
    for (int c = 0; c < NCH; c++) {
        u16* sg = base + (size_t)c * 4096;
        uint4 q0 = *(const uint4*)sg;
        uint4 q1 = *(const uint4*)(sg + 8);
        float sf[16]; unpack8(q0, sf); unpack8(q1, sf + 8);
        *(uint4*)sg       = pack8(hcur);       // h entering chunk c
        *(uint4*)(sg + 8) = pack8(hcur + 8);
        float dk = decay[dbh * 16 + c];
        #pragma unroll
        for (int i = 0; i < 16; i++) hcur[i] = dk * hcur[i] + sf[i];
    }
}

// ---------- inter-chunk contribution (parallel): y += (wout.*C) * h_in^T ----------
__global__ __launch_bounds__(256) void k_inter(const u16* __restrict__ BCb, const float* __restrict__ wout,
                                               const u16* __restrict__ hin, u16* __restrict__ y0,
                                               u16* __restrict__ y1) {
    __shared__ __align__(16) u16 Csc[128 * 72];      // wout[s]*C[s][n]
    __shared__ __align__(16) u16 hs[64 * 72];        // h_in[p][n], padded
    const int blk = blockIdx.x;
    const int c = blk & 15, dbh = blk >> 4;
    const int h = dbh & 31, b = (dbh >> 5) & 3, dir = dbh >> 7;
    const int tid = threadIdx.x, w = tid >> 6, lane = tid & 63, lr = lane & 15, lq = lane >> 4;
    u16* yo = dir ? y1 : y0;

    {   // stage h_in (p-major 64x64 -> padded rows)
        int g = tid * 16, p = g >> 6, n = g & 63;
        const u16* hg = hin + (size_t)blk * 4096 + g;
        *(uint4*)&hs[p * 72 + n]     = *(const uint4*)hg;
        *(uint4*)&hs[p * 72 + n + 8] = *(const uint4*)(hg + 8);
    }
    const int sl0 = tid >> 3, ng = (tid & 7) * 8;
    #pragma unroll
    for (int it = 0; it < 4; it++) {
        int sl = sl0 + it * 32;
        int s = c * QC + sl;
        int t = dir ? (L_ - 1 - s) : s;
        const u16* bcr = BCb + ((size_t)b * L_ + t) * 128 + 64 + ng;
        float sc = wout[dbh * 2048 + s];
        uint4 cv = *(const uint4*)bcr;
        float cf[8]; unpack8(cv, cf);
        float f[8] = {cf[0]*sc, cf[1]*sc, cf[2]*sc, cf[3]*sc, cf[4]*sc, cf[5]*sc, cf[6]*sc, cf[7]*sc};
        *(uint4*)&Csc[sl * 72 + ng] = pack8(f);
    }
    __syncthreads();
    f32x4 acc[2][4];
    #pragma unroll
    for (int ti = 0; ti < 2; ti++)
        #pragma unroll
        for (int pj = 0; pj < 4; pj++) acc[ti][pj] = (f32x4){0.f, 0.f, 0.f, 0.f};
    #pragma unroll
    for (int ks = 0; ks < 2; ks++) {
        bf16x8 a0 = *(const bf16x8*)&Csc[(w * 32 + lr) * 72 + ks * 32 + lq * 8];
        bf16x8 a1 = *(const bf16x8*)&Csc[(w * 32 + 16 + lr) * 72 + ks * 32 + lq * 8];
        #pragma unroll
        for (int pj = 0; pj < 4; pj++) {
            bf16x8 bb = *(const bf16x8*)&hs[(pj * 16 + lr) * 72 + ks * 32 + lq * 8];
            acc[0][pj] = __builtin_amdgcn_mfma_f32_16x16x32_bf16(a0, bb, acc[0][pj], 0, 0, 0);
            acc[1][pj] = __builtin_amdgcn_mfma_f32_16x16x32_bf16(a1, bb, acc[1][pj], 0, 0, 0);
        }
    }
    #pragma unroll
    for (int ti = 0; ti < 2; ti++)
        #pragma unroll
        for (int pj = 0; pj < 4; pj++)
            #pragma unroll
            for (int r = 0; r < 4; r++) {
                int t_l = w * 32 + ti * 16 + lq * 4 + r;
                int s = c * QC + t_l;
                int t = dir ? (L_ - 1 - s) : s;
                u16* yp = yo + ((size_t)b * L_ + t) * DIN + h * 64 + pj * 16 + lr;
                *yp = f2b(acc[ti][pj][r] + b2f(*yp));    // RMW own rows only — no races
            }
}

// ---------- gate + RMSNorm -> bf16 (shift folded into the y reads) ----------
__global__ __launch_bounds__(256) void k_gate(const u16* __restrict__ xs, const u16* __restrict__ zx,
                                              const u16* __restrict__ y0, const u16* __restrict__ y1,
                                              const float* __restrict__ Dd,
                                              const float* __restrict__ nw, u16* __restrict__ yn) {
    int row = blockIdx.x, tid = threadIdx.x;
    int t = row & (L_ - 1);
    __shared__ float red[4];
    size_t base = (size_t)row * DIN;
    uint4 xv = ((const uint4*)(xs + base))[tid];
    uint4 zv = ((const uint4*)(zx + (size_t)row * NPAD))[tid];
    uint4 zero4 = {0u, 0u, 0u, 0u};
    uint4 a0 = (t > 0)      ? ((const uint4*)(y0 + base - DIN))[tid] : zero4;   // y_fwd[t-1]
    uint4 a1 = (t < L_ - 1) ? ((const uint4*)(y1 + base + DIN))[tid] : zero4;   // y_bwd[t+1]
    float sD = Dd[(size_t)row * 32 + (tid >> 3)];
    float xf[8], zf[8], f0[8], f1[8];
    unpack8(xv, xf); unpack8(zv, zf); unpack8(a0, f0); unpack8(a1, f1);
    int d0 = tid * 8;
    float g[8]; float ss = 0.f;
    #pragma unroll
    for (int i = 0; i < 8; i++) {
        float yv = f0[i] + f1[i] + xf[i] * sD;
        float z = zf[i];
        float gg = yv * (z / (1.f + __expf(-z)));
        g[i] = gg; ss += gg * gg;
    }
    for (int o = 32; o; o >>= 1) ss += __shfl_down(ss, o);
    if ((tid & 63) == 0) red[tid >> 6] = ss;
    __syncthreads();
    float tot = red[0] + red[1] + red[2] + red[3];
    float r = rsqrtf(tot * (1.f / DIN) + EPS);
    float o8[8];
    #pragma unroll
    for (int i = 0; i < 8; i++) o8[i] = g[i] * r * nw[d0 + i];
    ((uint4*)(yn + base))[tid] = pack8(o8);
}

// ---------- workspace layout (bytes) ----------
#define OFF_U     ((size_t)0)                       // BL*DM bf16 (dead after GEMM1)
#define OFF_WIN   ((size_t)16777216)                // NPAD*DM bf16
#define OFF_WOUT  ((size_t)25690112)                // DM*DIN bf16
#define OFF_ZX    ((size_t)29884416)                // BL*NPAD bf16
#define OFF_XS    ((size_t)101187584)               // BL*DIN bf16
#define OFF_BC    ((size_t)134742016)               // BL*128 bf16 = 2 MB
#define OFF_DTA   ((size_t)138936320)               // (unused)
#define OFF_Y0    ((size_t)143130624)               // BL*DIN bf16
#define OFF_Y1    ((size_t)176685056)               // BL*DIN bf16
#define OFF_YN    ((size_t)210239488)               // BL*DIN bf16 (gate out); scb/h_in aliases earlier
// aliases inside dead OFF_U region:
#define OFF_WO2   OFF_U                             // 256*2048 f32 = 2 MB
#define OFF_DEC   (OFF_U + 2097152)                 // 4096 f32
#define OFF_FCB   (OFF_U + 2113536)                 // NH*DIN bf16 = 128 KB
#define OFF_DD    (OFF_U + 2244608)                 // BL*32 f32 = 1 MB
#define OFF_SCB   OFF_YN                            // 4096*4096 bf16 = 33.5 MB (S_c -> h_in in place; dead before k_gate writes yn)
// total 243,793,920 bytes

extern "C" void kernel_launch(void* const* d_in, const int* in_sizes, int n_in,
                              void* d_out, int out_size, void* d_ws, size_t ws_size,
                              hipStream_t stream) {
    const float* x       = (const float*)d_in[0];
    const float* ln_g    = (const float*)d_in[1];
    const float* ln_b    = (const float*)d_in[2];
    const float* W_in    = (const float*)d_in[3];
    const float* conv_w  = (const float*)d_in[4];
    const float* conv_b  = (const float*)d_in[5];
    const float* dt_bias = (const float*)d_in[6];
    const float* A_log   = (const float*)d_in[7];
    const float* fc_D_w  = (const float*)d_in[8];
    const float* Dv      = (const float*)d_in[9];
    const float* norm_w  = (const float*)d_in[10];
    const float* W_out   = (const float*)d_in[11];

    char* ws = (char*)d_ws;
    u16*   u_bf  = (u16*)(ws + OFF_U);
    u16*   winb  = (u16*)(ws + OFF_WIN);
    u16*   woutb = (u16*)(ws + OFF_WOUT);
    u16*   zx    = (u16*)(ws + OFF_ZX);
    u16*   xs    = (u16*)(ws + OFF_XS);
    u16*   BCb   = (u16*)(ws + OFF_BC);
    u16*   y0b   = (u16*)(ws + OFF_Y0);
    u16*   y1b   = (u16*)(ws + OFF_Y1);
    u16*   ynb   = (u16*)(ws + OFF_YN);
    float* wo2   = (float*)(ws + OFF_WO2);
    float* dec   = (float*)(ws + OFF_DEC);
    u16*   fcb   = (u16*)(ws + OFF_FCB);
    float* Dd    = (float*)(ws + OFF_DD);
    u16*   scb   = (u16*)(ws + OFF_SCB);

    k_cvt_win <<<(NPAD * DM) / 256, 256, 0, stream>>>(W_in, winb);
    k_cvt_wout<<<(DM * DIN) / 256, 256, 0, stream>>>(W_out, woutb);
    k_ln      <<<BL, 256, 0, stream>>>(x, ln_g, ln_b, u_bf);
    k_gemm256 <<<(NPAD / 256) * (BL / 256), 512, 0, stream>>>(u_bf, winb, DM, zx, NPAD);
    k_cvt_fcd <<<(NH * DIN) / 256, 256, 0, stream>>>(fc_D_w, fcb);
    k_conv    <<<dim3(CONV_DIM / 64, L_ / 256, B_), 256, 0, stream>>>(zx, conv_w, conv_b, xs, BCb);
    k_dproj   <<<BL / 32, 256, 0, stream>>>(xs, fcb, Dv, Dd);
    k_chunk   <<<4096, 256, 0, stream>>>(xs, BCb, zx, dt_bias, A_log, y0b, y1b, wo2, dec, scb);
    k_hscan   <<<256, 256, 0, stream>>>(dec, scb);
    k_inter   <<<4096, 256, 0, stream>>>(BCb, wo2, scb, y0b, y1b);
    k_gate    <<<BL, 256, 0, stream>>>(xs, zx, y0b, y1b, Dd, norm_w, ynb);
    k_gemm_bt <<<dim3(DM / 128, BL / 128), 256, 0, stream>>>(ynb, woutb, BL, DM, DIN, 0, nullptr, DM, (float*)d_out, x);
}

// Round 4
// 535.335 us; speedup vs baseline: 1.0199x; 1.0199x over previous
//
#include <hip/hip_runtime.h>
#include <stdint.h>

// ---- problem constants ----
#define B_   4
#define L_   2048
#define DM   1024
#define DIN  2048
#define NH   32
#define HD   64
#define DSTATE 64
#define DCONV  7
#define CONV_DIM 2176            // DIN + 2*DSTATE
#define DPROJ 4288               // 2*DIN + 2*DSTATE + 2*NH
#define NPAD 4352                // DPROJ padded to 128 (= 17*256)
#define BL   8192                // B_*L_
#define EPS  1e-5f
#define QC   128                 // scan chunk length
#define NCH  16                  // chunks per sequence

typedef unsigned short u16;
typedef unsigned int   u32;
typedef __bf16 bf16x8 __attribute__((ext_vector_type(8)));
typedef float  f32x4  __attribute__((ext_vector_type(4)));

__device__ __forceinline__ float b2f(u32 b) { return __uint_as_float(b << 16); }
__device__ __forceinline__ u16 f2b(float f) {
    u32 u = __float_as_uint(f);
    u32 r = (u + 0x7fffu + ((u >> 16) & 1u)) >> 16;
    return (u16)r;
}
__device__ __forceinline__ void unpack8(uint4 v, float* f) {
    f[0] = b2f(v.x & 0xffffu); f[1] = b2f(v.x >> 16);
    f[2] = b2f(v.y & 0xffffu); f[3] = b2f(v.y >> 16);
    f[4] = b2f(v.z & 0xffffu); f[5] = b2f(v.z >> 16);
    f[6] = b2f(v.w & 0xffffu); f[7] = b2f(v.w >> 16);
}
__device__ __forceinline__ uint4 pack8(const float* f) {
    uint4 v;
    v.x = (u32)f2b(f[0]) | ((u32)f2b(f[1]) << 16);
    v.y = (u32)f2b(f[2]) | ((u32)f2b(f[3]) << 16);
    v.z = (u32)f2b(f[4]) | ((u32)f2b(f[5]) << 16);
    v.w = (u32)f2b(f[6]) | ((u32)f2b(f[7]) << 16);
    return v;
}
// skewed LDS index for transposed tiles: row-stride 136 u16 + 8-u16 skew per 8 rows.
__device__ __forceinline__ int xts(int p, int s) { return p * 136 + ((p >> 3) << 3) + s; }
// async global->LDS, 16B per lane; lds base must be wave-uniform (HW adds lane*16)
__device__ __forceinline__ void gload_lds16(const u16* g, u16* l) {
    __builtin_amdgcn_global_load_lds((const __attribute__((address_space(1))) void*)g,
                                     (__attribute__((address_space(3))) void*)l, 16, 0, 0);
}

// ---------- weight conversion ----------
__global__ __launch_bounds__(256) void k_cvt_win(const float* __restrict__ W, u16* __restrict__ Wb) {
    int idx = blockIdx.x * 256 + threadIdx.x;      // over NPAD*DM
    int n = idx >> 10;                              // DM = 1024
    float v = (n < DPROJ) ? W[(size_t)n * DM + (idx & 1023)] : 0.f;
    Wb[idx] = f2b(v);
}
__global__ __launch_bounds__(256) void k_cvt_wout(const float* __restrict__ W, u16* __restrict__ Wb) {
    int idx = blockIdx.x * 256 + threadIdx.x;      // over DM*DIN
    Wb[idx] = f2b(W[idx]);
}
__global__ __launch_bounds__(256) void k_cvt_fcd(const float* __restrict__ W, u16* __restrict__ Wb) {
    int idx = blockIdx.x * 256 + threadIdx.x;      // over NH*DIN
    Wb[idx] = f2b(W[idx]);
}

// ---------- layernorm -> bf16 ----------
__global__ __launch_bounds__(256) void k_ln(const float* __restrict__ x, const float* __restrict__ g,
                                            const float* __restrict__ be, u16* __restrict__ u) {
    int row = blockIdx.x, tid = threadIdx.x;
    const float4* xr = (const float4*)(x + (size_t)row * DM);
    float4 v = xr[tid];
    float s1 = v.x + v.y + v.z + v.w;
    float s2 = v.x * v.x + v.y * v.y + v.z * v.z + v.w * v.w;
    for (int o = 32; o; o >>= 1) { s1 += __shfl_down(s1, o); s2 += __shfl_down(s2, o); }
    __shared__ float ls1[4], ls2[4];
    int w = tid >> 6;
    if ((tid & 63) == 0) { ls1[w] = s1; ls2[w] = s2; }
    __syncthreads();
    float t1 = ls1[0] + ls1[1] + ls1[2] + ls1[3];
    float t2 = ls2[0] + ls2[1] + ls2[2] + ls2[3];
    float mu = t1 * (1.f / DM);
    float var = t2 * (1.f / DM) - mu * mu;
    float rs = rsqrtf(var + EPS);
    float4 gv = ((const float4*)g)[tid];
    float4 bv = ((const float4*)be)[tid];
    float o0 = (v.x - mu) * rs * gv.x + bv.x;
    float o1 = (v.y - mu) * rs * gv.y + bv.y;
    float o2 = (v.z - mu) * rs * gv.z + bv.z;
    float o3 = (v.w - mu) * rs * gv.w + bv.w;
    uint2 p;
    p.x = (u32)f2b(o0) | ((u32)f2b(o1) << 16);
    p.y = (u32)f2b(o2) | ((u32)f2b(o3) << 16);
    ((uint2*)(u + (size_t)row * DM))[tid] = p;
}

// ======================================================================
// 256x256-tile bf16 GEMM, m201-style 8-phase schedule. C[m,n] = sum_k A[m,k]*B[n,k].
// BK=64 split in two K-half slabs of 256 rows x 32 cols (16 KB each).
// LDS = 2(dbuf, K-tile parity) x 2(k-half) x {A,B} x 16 KB = 128 KiB.
// Iteration i covers tiles t=2i (d0), t+1 (d1); 8 phases, each:
//   {ds_read frags ; stage ONE slab ; barrier ; lgkmcnt(0) ; sched_barrier ;
//    setprio(1) ; 16 MFMA ; setprio(0) ; [vmcnt(10) on even phases] ; barrier}
// The vmcnt sits at the END of even phases so the CLOSING barrier guarantees
// the next odd phase's slabs are fully landed (all waves). Forced-completion
// distance = 6 phases (~1000 cyc >= HBM latency); 14 loads max in flight,
// never drained below 10 until the tail.
// Stage schedule (earliest-legal; every stage >=1 barrier after that slab's
// LAST read, A-slabs are read in TWO consecutive phases):
//   p1:A11(t+1)  p2:B00(t+2)  p3:A00(t+2)  p4:B01(t+2)
//   p5:A01(t+2)  p6:B10(t+3)  p7:A10(t+3)  p8:B11(t+3)
// Reads: p1/p2: A00,B00[t] ; p3/p4: A01,B01[t] ; p5/p6: A10,B10[t+1] ;
//        p7/p8: A11,B11[t+1].  Drain check (per-wave queue, 2 loads/slab):
//   p2-end drains prev{B01,A01}, p4-end prev{B10,A10}, p6-end {prev B11, p1
//   A11}, p8-end {p2 B00, p3 A00} -- exactly the slabs the next odd phase
//   reads.  Prologue: A00,B00,B01,A01,B10,A10,B11 (7 slabs) + vmcnt(10).
// Swizzle: chunk c holds global chunk c^((r>>1)&3); gload src pre-swizzled,
// ds_read same XOR -> 0 bank conflicts (measured rounds 1-3).
// Grid: 1-D 544 blocks, bijective XCD-chunked swizzle (544 = 8*68).
// Requires M%256==0, N%256==0, K%128==0, K>=256 (NI>=2).
// ======================================================================
#define G3_DSA(d, kh, ms)                                                        \
  { _Pragma("unroll")                                                            \
    for (int mi = 0; mi < 4; mi++)                                               \
      af_[mi] = *(const bf16x8*)&Asl[d][kh][a_rd + (ms) * 2048 + mi * 512]; }
#define G3_DSB(d, kh)                                                            \
  { _Pragma("unroll")                                                            \
    for (int nj = 0; nj < 4; nj++)                                               \
      bf_[nj] = *(const bf16x8*)&Bsl[d][kh][b_rd + nj * 512]; }
#define G3_STA(d, kh, tau)                                                       \
  { const size_t ko = (size_t)((tau) * 64 + (kh) * 32);                          \
    gload_lds16(Ag + a_src + ko, &Asl[d][kh][st_l]);                             \
    gload_lds16(Ag + a_src + srowK + ko, &Asl[d][kh][st_l + 512]); }
#define G3_STB(d, kh, tau)                                                       \
  { const size_t ko = (size_t)((tau) * 64 + (kh) * 32);                          \
    gload_lds16(Bg + b_src + ko, &Bsl[d][kh][st_l]);                             \
    gload_lds16(Bg + b_src + srowK + ko, &Bsl[d][kh][st_l + 512]); }
#define G3_CORE(ms)                                                              \
    __builtin_amdgcn_s_barrier();                                                \
    asm volatile("s_waitcnt lgkmcnt(0)" ::: "memory");                           \
    __builtin_amdgcn_sched_barrier(0);                                           \
    __builtin_amdgcn_s_setprio(1);                                               \
    _Pragma("unroll")                                                            \
    for (int mi = 0; mi < 4; mi++)                                               \
      _Pragma("unroll")                                                          \
      for (int nj = 0; nj < 4; nj++)                                             \
        acc[ms][mi][nj] = __builtin_amdgcn_mfma_f32_16x16x32_bf16(af_[mi], bf_[nj], acc[ms][mi][nj], 0, 0, 0); \
    __builtin_amdgcn_s_setprio(0);                                               \
    __builtin_amdgcn_sched_barrier(0);
#define G3_MMO(ms)                                                               \
  { G3_CORE(ms)                                                                  \
    __builtin_amdgcn_s_barrier();                                                \
    asm volatile("" ::: "memory"); }
#define G3_MME(ms, VM)                                                           \
  { G3_CORE(ms)                                                                  \
    asm volatile("s_waitcnt vmcnt(" #VM ")" ::: "memory");                       \
    __builtin_amdgcn_s_barrier();                                                \
    asm volatile("" ::: "memory"); }

__global__ __launch_bounds__(512, 2) void k_gemm256(const u16* __restrict__ Ag, const u16* __restrict__ Bg,
                                                    int K, u16* __restrict__ obf, int ldo) {
    __shared__ __align__(16) u16 Asl[2][2][8192];   // [dbuf][khalf][256 rows x 32 cols]
    __shared__ __align__(16) u16 Bsl[2][2][8192];
    const int tid = threadIdx.x;
    const int w = tid >> 6, lane = tid & 63, lr = lane & 15, lq = lane >> 4;
    const int wm = w >> 2, wn = w & 3;                    // 2 (M) x 4 (N) waves
    // bijective XCD-chunked swizzle: 544 blocks = 8 XCDs x 68; column-chunked decode
    const int bid = blockIdx.x;
    const int swz = (bid & 7) * 68 + (bid >> 3);
    const int bx = swz >> 5, by = swz & 31;               // bx: N-block (0..16), by: M-block (0..31)
    const int m0 = by * 256, n0 = bx * 256;
    // staging: lane -> row lane>>2 (16 rows/gload), chunk lane&3, src pre-swizzled
    const int sr = lane >> 2;
    const int sc = (lane & 3) ^ ((lane >> 3) & 3);
    const size_t a_src = (size_t)(m0 + w * 32 + sr) * K + sc * 8;
    const size_t b_src = (size_t)(n0 + w * 32 + sr) * K + sc * 8;
    const size_t srowK = (size_t)16 * K;
    const int st_l = w * 1024;                            // wave-uniform LDS dst (u16)
    // ds_read addressing (swizzled chunk)
    const int swc = (lq ^ ((lr >> 1) & 3)) << 3;
    const int a_rd = (wm * 128 + lr) * 32 + swc;
    const int b_rd = (wn * 64 + lr) * 32 + swc;

    f32x4 acc[2][4][4];
    #pragma unroll
    for (int s = 0; s < 2; s++)
        #pragma unroll
        for (int i = 0; i < 4; i++)
            #pragma unroll
            for (int j = 0; j < 4; j++) acc[s][i][j] = (f32x4){0.f, 0.f, 0.f, 0.f};

    bf16x8 af_[4], bf_[4];

    // prologue: issue order A00(0),B00(0),B01(0),A01(0),B10(1),A10(1),B11(1)
    G3_STA(0, 0, 0); G3_STB(0, 0, 0);
    G3_STB(0, 1, 0); G3_STA(0, 1, 0);
    G3_STB(1, 0, 1); G3_STA(1, 0, 1);
    G3_STB(1, 1, 1);
    asm volatile("s_waitcnt vmcnt(10)" ::: "memory");      // drain A00(0),B00(0)
    __builtin_amdgcn_s_barrier();
    asm volatile("" ::: "memory");

    const int NI = K >> 7;                                // iterations (2 K-tiles each), >= 2
    for (int i = 0; i < NI - 1; ++i) {
        const int t = 2 * i;
        G3_DSB(0, 0) G3_DSA(0, 0, 0) G3_STA(1, 1, t + 1);  G3_MMO(0)       // p1
        G3_DSA(0, 0, 1) G3_STB(0, 0, t + 2);               G3_MME(1, 10)   // p2
        G3_DSB(0, 1) G3_DSA(0, 1, 0) G3_STA(0, 0, t + 2);  G3_MMO(0)       // p3
        G3_DSA(0, 1, 1) G3_STB(0, 1, t + 2);               G3_MME(1, 10)   // p4
        G3_DSB(1, 0) G3_DSA(1, 0, 0) G3_STA(0, 1, t + 2);  G3_MMO(0)       // p5
        G3_DSA(1, 0, 1) G3_STB(1, 0, t + 3);               G3_MME(1, 10)   // p6
        G3_DSB(1, 1) G3_DSA(1, 1, 0) G3_STA(1, 0, t + 3);  G3_MMO(0)       // p7
        G3_DSA(1, 1, 1) G3_STB(1, 1, t + 3);               G3_MME(1, 10)   // p8
    }
    {   // last iteration: stage only A11(t+1) at p1; drain 8 -> 4 -> 0
        const int t = 2 * (NI - 1);
        G3_DSB(0, 0) G3_DSA(0, 0, 0) G3_STA(1, 1, t + 1);  G3_MMO(0)
        G3_DSA(0, 0, 1);                                   G3_MME(1, 8)
        G3_DSB(0, 1) G3_DSA(0, 1, 0);                      G3_MMO(0)
        G3_DSA(0, 1, 1);                                   G3_MME(1, 4)
        G3_DSB(1, 0) G3_DSA(1, 0, 0);                      G3_MMO(0)
        G3_DSA(1, 0, 1);                                   G3_MME(1, 0)
        G3_DSB(1, 1) G3_DSA(1, 1, 0);                      G3_MMO(0)
        G3_DSA(1, 1, 1);                                   G3_MMO(1)
    }

    #pragma unroll
    for (int ms = 0; ms < 2; ms++)
        #pragma unroll
        for (int mi = 0; mi < 4; mi++)
            #pragma unroll
            for (int nj = 0; nj < 4; nj++)
                #pragma unroll
                for (int rr = 0; rr < 4; rr++) {
                    int m = m0 + wm * 128 + ms * 64 + mi * 16 + lq * 4 + rr;
                    int n = n0 + wn * 64 + nj * 16 + lr;
                    obf[(size_t)m * ldo + n] = f2b(acc[ms][mi][nj][rr]);
                }
}

// ---------- bf16 MFMA GEMM, C[m,n] = sum_k A[m,k]*B[n,k]  (B^T layout) ----------
__global__ __launch_bounds__(256) void k_gemm_bt(const u16* __restrict__ A, const u16* __restrict__ Bw,
                                                 int M, int N, int K, int out_bf16,
                                                 u16* __restrict__ obf, int ldo,
                                                 float* __restrict__ ofp, const float* __restrict__ res) {
    __shared__ __align__(16) u16 As[128 * 64];
    __shared__ __align__(16) u16 Bs[128 * 64];
    int tid = threadIdx.x;
    int m0 = blockIdx.y * 128, n0 = blockIdx.x * 128;
    int w = tid >> 6, lane = tid & 63;
    int wm = (w >> 1) * 64, wn = (w & 1) * 64;
    int lr = lane & 15, lq = lane >> 4;

    f32x4 acc[4][4];
    #pragma unroll
    for (int i = 0; i < 4; i++)
        #pragma unroll
        for (int j = 0; j < 4; j++) acc[i][j] = (f32x4){0.f, 0.f, 0.f, 0.f};

    for (int kt = 0; kt < K; kt += 64) {
        #pragma unroll
        for (int it = 0; it < 4; it++) {
            int s_idx = it * 256 + tid;
            int row = s_idx >> 3;
            int kcg = (s_idx & 7) ^ (row & 7);            // swizzled source chunk
            u16* lbase_a = &As[(it * 256 + w * 64) * 8];  // wave-uniform
            u16* lbase_b = &Bs[(it * 256 + w * 64) * 8];
            gload_lds16(A + (size_t)(m0 + row) * K + kt + kcg * 8, lbase_a);
            gload_lds16(Bw + (size_t)(n0 + row) * K + kt + kcg * 8, lbase_b);
        }
        __syncthreads();
        #pragma unroll
        for (int kk = 0; kk < 2; kk++) {
            bf16x8 af[4], bfr[4];
            #pragma unroll
            for (int i = 0; i < 4; i++) {
                int row = wm + 16 * i + lr;
                af[i] = *(const bf16x8*)&As[row * 64 + (((kk * 4 + lq)) ^ (row & 7)) * 8];
            }
            #pragma unroll
            for (int j = 0; j < 4; j++) {
                int row = wn + 16 * j + lr;
                bfr[j] = *(const bf16x8*)&Bs[row * 64 + (((kk * 4 + lq)) ^ (row & 7)) * 8];
            }
            #pragma unroll
            for (int i = 0; i < 4; i++)
                #pragma unroll
                for (int j = 0; j < 4; j++)
                    acc[i][j] = __builtin_amdgcn_mfma_f32_16x16x32_bf16(af[i], bfr[j], acc[i][j], 0, 0, 0);
        }
        __syncthreads();
    }
    #pragma unroll
    for (int i = 0; i < 4; i++) {
        #pragma unroll
        for (int j = 0; j < 4; j++) {
            #pragma unroll
            for (int rr = 0; rr < 4; rr++) {
                int m = m0 + wm + 16 * i + lq * 4 + rr;
                int n = n0 + wn + 16 * j + lr;
                float v = acc[i][j][rr];
                if (out_bf16) obf[(size_t)m * ldo + n] = f2b(v);
                else          ofp[(size_t)m * ldo + n] = v + res[(size_t)m * ldo + n];
            }
        }
    }
}

// ---------- D-projection GEMM: Dd[m][h] = dot(xs[m,:], fc_D_w[h,:]) + Dv[h] ----------
__global__ __launch_bounds__(256) void k_dproj(const u16* __restrict__ xs, const u16* __restrict__ fcb,
                                               const float* __restrict__ Dv, float* __restrict__ Dd) {
    __shared__ __align__(16) u16 As[32 * 72];
    __shared__ __align__(16) u16 Bs[32 * 72];
    int tid = threadIdx.x;
    int m0 = blockIdx.x * 32;
    int w = tid >> 6, lane = tid & 63, lr = lane & 15, lq = lane >> 4;
    int mt = (w & 1) * 16, nt = (w >> 1) * 16;
    int r = tid >> 3, kc = tid & 7;
    f32x4 acc = (f32x4){0.f, 0.f, 0.f, 0.f};
    for (int kt = 0; kt < DIN; kt += 64) {
        *(uint4*)&As[r * 72 + kc * 8] = *(const uint4*)(xs + (size_t)(m0 + r) * DIN + kt + kc * 8);
        *(uint4*)&Bs[r * 72 + kc * 8] = *(const uint4*)(fcb + (size_t)r * DIN + kt + kc * 8);
        __syncthreads();
        #pragma unroll
        for (int ks = 0; ks < 2; ks++) {
            bf16x8 a = *(const bf16x8*)&As[(mt + lr) * 72 + ks * 32 + lq * 8];
            bf16x8 b = *(const bf16x8*)&Bs[(nt + lr) * 72 + ks * 32 + lq * 8];
            acc = __builtin_amdgcn_mfma_f32_16x16x32_bf16(a, b, acc, 0, 0, 0);
        }
        __syncthreads();
    }
    #pragma unroll
    for (int rr = 0; rr < 4; rr++) {
        int m = m0 + mt + lq * 4 + rr;
        int n = nt + lr;
        Dd[(size_t)m * 32 + n] = acc[rr] + Dv[n];
    }
}

// ---------- depthwise conv7 (same-pad) + bias + SiLU, split xs / BC(bf16) ----------
__global__ __launch_bounds__(256) void k_conv(const u16* __restrict__ zx, const float* __restrict__ cw,
                                              const float* __restrict__ cb, u16* __restrict__ xs,
                                              u16* __restrict__ BCb) {
    __shared__ u16 sh[262 * 64];
    int c0 = blockIdx.x * 64, t0 = blockIdx.y * 256, b = blockIdx.z;
    int tid = threadIdx.x;
    int c = tid & 63, tg = tid >> 6;
    for (int it = 0; it < 66; it++) {
        int r = it * 4 + tg;
        if (r < 262) {
            int t = t0 + r - 3;
            u16 v = 0;
            if (t >= 0 && t < L_) v = zx[(size_t)(b * L_ + t) * NPAD + DIN + c0 + c];
            sh[r * 64 + c] = v;
        }
    }
    float wgt[7];
    #pragma unroll
    for (int k = 0; k < 7; k++) wgt[k] = cw[(c0 + c) * 7 + k];
    float bias = cb[c0 + c];
    __syncthreads();
    int cg = c0 + c;
    for (int tt = 0; tt < 64; tt++) {
        int tl = tt * 4 + tg;
        float a = bias;
        #pragma unroll
        for (int k = 0; k < 7; k++) a += b2f(sh[(tl + k) * 64 + c]) * wgt[k];
        float v = a / (1.f + __expf(-a));   // silu
        size_t row = (size_t)b * L_ + (t0 + tl);
        if (cg < DIN) xs[row * DIN + cg] = f2b(v);
        else          BCb[row * 128 + (cg - DIN)] = f2b(v);   // B at [0,64), C at [64,128), bf16
    }
}

// ======================================================================
// Chunked SSD scan (intra-chunk + chunk-state + inline dt): block = (dir,b,h,chunk).
// ======================================================================
__global__ __launch_bounds__(256) void k_chunk(const u16* __restrict__ xs, const u16* __restrict__ BCb,
                                               const u16* __restrict__ zx, const float* __restrict__ dt_bias,
                                               const float* __restrict__ A_log, u16* __restrict__ y0,
                                               u16* __restrict__ y1, float* __restrict__ wout,
                                               float* __restrict__ decay, u16* __restrict__ scb) {
    __shared__ __align__(16) u16 ab[18432];      // Cs [0,9216) stride 72, Bs [9216,18432); S overlays (skewed 136)
    __shared__ __align__(16) u16 XT[8768];       // X^T [p][s] skewed
    __shared__ __align__(16) u16 BT[8768];       // B^T [n][s] skewed
    __shared__ __align__(16) float dts_s[128];
    __shared__ __align__(16) float lda_s[128];
    __shared__ __align__(16) float wend[128];
    __shared__ __align__(16) double cumd[128];

    const int blk = blockIdx.x;
    const int c = blk & 15, dbh = blk >> 4;
    const int h = dbh & 31, b = (dbh >> 5) & 3, dir = dbh >> 7;
    const int tid = threadIdx.x, w = tid >> 6, lane = tid & 63, lr = lane & 15, lq = lane >> 4;
    const int s0 = c * QC;
    u16* yo = dir ? y1 : y0;

    if (tid < 128) {   // inline dt2 / log-dA
        int s = s0 + tid;
        int t = dir ? (L_ - 1 - s) : s;
        float draw = b2f(zx[(size_t)(b * L_ + t) * NPAD + (DIN + CONV_DIM) + dir * 32 + h]);
        float xb = draw + dt_bias[h];
        float dt2 = (xb > 20.f) ? xb : log1pf(__expf(xb));
        dts_s[tid] = dt2;
        lda_s[tid] = -__expf(A_log[h]) * dt2;
    }
    {   // stage Cs, Bs (bf16 row-major), BT, XT (transposed, skewed)
        int sl0 = tid >> 3, ng = (tid & 7) * 8;
        #pragma unroll
        for (int it = 0; it < 4; it++) {
            int sl = sl0 + it * 32;
            int s = s0 + sl;
            int t = dir ? (L_ - 1 - s) : s;
            size_t row = (size_t)b * L_ + t;
            const u16* bcr = BCb + row * 128;
            uint4 cv = *(const uint4*)(bcr + 64 + ng);
            *(uint4*)&ab[sl * 72 + ng] = cv;
            uint4 pb = *(const uint4*)(bcr + ng);
            *(uint4*)&ab[9216 + sl * 72 + ng] = pb;
            u16 bh[8] = {(u16)(pb.x & 0xffffu), (u16)(pb.x >> 16), (u16)(pb.y & 0xffffu), (u16)(pb.y >> 16),
                         (u16)(pb.z & 0xffffu), (u16)(pb.z >> 16), (u16)(pb.w & 0xffffu), (u16)(pb.w >> 16)};
            #pragma unroll
            for (int i = 0; i < 8; i++) BT[(ng + i) * 136 + ng + sl] = bh[i];   // skew = ng
            uint4 xv = *(const uint4*)(xs + row * DIN + h * 64 + ng);
            u16 xh[8] = {(u16)(xv.x & 0xffffu), (u16)(xv.x >> 16), (u16)(xv.y & 0xffffu), (u16)(xv.y >> 16),
                         (u16)(xv.z & 0xffffu), (u16)(xv.z >> 16), (u16)(xv.w & 0xffffu), (u16)(xv.w >> 16)};
            #pragma unroll
            for (int i = 0; i < 8; i++) XT[(ng + i) * 136 + ng + sl] = xh[i];   // skew = ng
        }
    }
    __syncthreads();
    if (w == 0) {   // double-precision inclusive prefix of log-dA (wave 0)
        double v0 = (double)lda_s[lane];
        double v1 = (double)lda_s[64 + lane];
        #pragma unroll
        for (int o = 1; o < 64; o <<= 1) {
            double t0 = __shfl_up(v0, o);
            double t1 = __shfl_up(v1, o);
            if (lane >= o) { v0 += t0; v1 += t1; }
        }
        double tot0 = __shfl(v0, 63);
        cumd[lane] = v0;
        cumd[64 + lane] = tot0 + v1;
    }
    // G = C * B^T  (wave w owns t-rows [w*32, w*32+32))
    bf16x8 af[2][2];
    #pragma unroll
    for (int ti = 0; ti < 2; ti++)
        #pragma unroll
        for (int ks = 0; ks < 2; ks++)
            af[ti][ks] = *(const bf16x8*)&ab[(w * 32 + ti * 16 + lr) * 72 + ks * 32 + lq * 8];
    f32x4 accg[2][8];
    #pragma unroll
    for (int ti = 0; ti < 2; ti++)
        #pragma unroll
        for (int si = 0; si < 8; si++) accg[ti][si] = (f32x4){0.f, 0.f, 0.f, 0.f};
    #pragma unroll
    for (int si = 0; si < 8; si++)
        #pragma unroll
        for (int ks = 0; ks < 2; ks++) {
            bf16x8 bf = *(const bf16x8*)&ab[9216 + (si * 16 + lr) * 72 + ks * 32 + lq * 8];
            accg[0][si] = __builtin_amdgcn_mfma_f32_16x16x32_bf16(af[0][ks], bf, accg[0][si], 0, 0, 0);
            accg[1][si] = __builtin_amdgcn_mfma_f32_16x16x32_bf16(af[1][ks], bf, accg[1][si], 0, 0, 0);
        }
    __syncthreads();   // all G frag reads done; cumd ready
    // wend[s] = exp(cum[127]-cum[s])*dt[s]  (for chunk-state); visible after next barrier
    if (tid < 128) wend[tid] = __expf((float)(cumd[127] - cumd[tid])) * dts_s[tid];
    // S = M .* G  -> overlay into ab (skewed stride 136)
    {
        double cumt_d[8];
        #pragma unroll
        for (int ti = 0; ti < 2; ti++)
            #pragma unroll
            for (int r = 0; r < 4; r++) cumt_d[ti * 4 + r] = cumd[w * 32 + ti * 16 + lq * 4 + r];
        double cums_d[8]; float dts_l[8];
        #pragma unroll
        for (int si = 0; si < 8; si++) { cums_d[si] = cumd[si * 16 + lr]; dts_l[si] = dts_s[si * 16 + lr]; }
        #pragma unroll
        for (int ti = 0; ti < 2; ti++)
            #pragma unroll
            for (int si = 0; si < 8; si++)
                #pragma unroll
                for (int r = 0; r < 4; r++) {
                    int t_l = w * 32 + ti * 16 + lq * 4 + r;
                    int s_l = si * 16 + lr;
                    float v = 0.f;
                    if (s_l <= t_l)
                        v = __expf((float)(cumt_d[ti * 4 + r] - cums_d[si])) * dts_l[si] * accg[ti][si][r];
                    ab[xts(t_l, s_l)] = f2b(v);
                }
    }
    __syncthreads();
    // Y_intra = S * X^T
    f32x4 acc[2][4];
    #pragma unroll
    for (int ti = 0; ti < 2; ti++)
        #pragma unroll
        for (int pj = 0; pj < 4; pj++) acc[ti][pj] = (f32x4){0.f, 0.f, 0.f, 0.f};
    #pragma unroll
    for (int ks = 0; ks < 4; ks++) {
        bf16x8 a0 = *(const bf16x8*)&ab[xts(w * 32 + lr, ks * 32 + lq * 8)];
        bf16x8 a1 = *(const bf16x8*)&ab[xts(w * 32 + 16 + lr, ks * 32 + lq * 8)];
        #pragma unroll
        for (int pj = 0; pj < 4; pj++) {
            bf16x8 bf = *(const bf16x8*)&XT[xts(pj * 16 + lr, ks * 32 + lq * 8)];
            acc[0][pj] = __builtin_amdgcn_mfma_f32_16x16x32_bf16(a0, bf, acc[0][pj], 0, 0, 0);
            acc[1][pj] = __builtin_amdgcn_mfma_f32_16x16x32_bf16(a1, bf, acc[1][pj], 0, 0, 0);
        }
    }
    #pragma unroll
    for (int ti = 0; ti < 2; ti++)
        #pragma unroll
        for (int pj = 0; pj < 4; pj++)
            #pragma unroll
            for (int r = 0; r < 4; r++) {
                int t_l = w * 32 + ti * 16 + lq * 4 + r;
                int s = s0 + t_l;
                int t = dir ? (L_ - 1 - s) : s;
                yo[((size_t)b * L_ + t) * DIN + h * 64 + pj * 16 + lr] = f2b(acc[ti][pj][r]);
            }
    // chunk state S_c[p][n] = sum_s wend[s]*x[s][p]*B[s][n]
    f32x4 accs[4];
    #pragma unroll
    for (int nj = 0; nj < 4; nj++) accs[nj] = (f32x4){0.f, 0.f, 0.f, 0.f};
    #pragma unroll
    for (int ks = 0; ks < 4; ks++) {
        uint4 xv = *(const uint4*)&XT[xts(w * 16 + lr, ks * 32 + lq * 8)];
        float xf[8]; unpack8(xv, xf);
        float4 w0 = *(const float4*)&wend[ks * 32 + lq * 8];
        float4 w1 = *(const float4*)&wend[ks * 32 + lq * 8 + 4];
        float fs[8] = {xf[0]*w0.x, xf[1]*w0.y, xf[2]*w0.z, xf[3]*w0.w,
                       xf[4]*w1.x, xf[5]*w1.y, xf[6]*w1.z, xf[7]*w1.w};
        bf16x8 a = __builtin_bit_cast(bf16x8, pack8(fs));
        #pragma unroll
        for (int nj = 0; nj < 4; nj++) {
            bf16x8 bb = *(const bf16x8*)&BT[xts(nj * 16 + lr, ks * 32 + lq * 8)];
            accs[nj] = __builtin_amdgcn_mfma_f32_16x16x32_bf16(a, bb, accs[nj], 0, 0, 0);
        }
    }
    #pragma unroll
    for (int nj = 0; nj < 4; nj++)
        #pragma unroll
        for (int r = 0; r < 4; r++) {
            int p = w * 16 + lq * 4 + r, n = nj * 16 + lr;
            scb[(size_t)blk * 4096 + p * 64 + n] = f2b(accs[nj][r]);
        }
    if (tid < 128) wout[dbh * 2048 + s0 + tid] = __expf((float)cumd[tid]);
    if (tid == 0)  decay[blk] = __expf((float)cumd[127]);
}

// ---------- h-state scan (barrier-free): rewrites scb slots in place with h_in per chunk ----------
// thread owns 16 (p,n) elements; the recurrence h = decay*h + S_c is elementwise.
__global__ __launch_bounds__(256) void k_hscan(const float* __restrict__ decay, u16* __restrict__ scb) {
    int dbh = blockIdx.x, tid = threadIdx.x;
    u16* base = scb + (size_t)dbh * 16 * 4096 + tid * 16;
    float hcur[16];
    #pragma unroll
    for (int i = 0; i < 16; i++) hcur[i] = 0.f;
    for (int c = 0; c < NCH; c++) {
        u16* sg = base + (size_t)c * 4096;
        uint4 q0 = *(const uint4*)sg;
        uint4 q1 = *(const uint4*)(sg + 8);
        float sf[16]; unpack8(q0, sf); unpack8(q1, sf + 8);
        *(uint4*)sg       = pack8(hcur);       // h entering chunk c
        *(uint4*)(sg + 8) = pack8(hcur + 8);
        float dk = decay[dbh * 16 + c];
        #pragma unroll
        for (int i = 0; i < 16; i++) hcur[i] = dk * hcur[i] + sf[i];
    }
}

// ---------- inter-chunk contribution (parallel): y += (wout.*C) * h_in^T ----------
__global__ __launch_bounds__(256) void k_inter(const u16* __restrict__ BCb, const float* __restrict__ wout,
                                               const u16* __restrict__ hin, u16* __restrict__ y0,
                                               u16* __restrict__ y1) {
    __shared__ __align__(16) u16 Csc[128 * 72];      // wout[s]*C[s][n]
    __shared__ __align__(16) u16 hs[64 * 72];        // h_in[p][n], padded
    const int blk = blockIdx.x;
    const int c = blk & 15, dbh = blk >> 4;
    const int h = dbh & 31, b = (dbh >> 5) & 3, dir = dbh >> 7;
    const int tid = threadIdx.x, w = tid >> 6, lane = tid & 63, lr = lane & 15, lq = lane >> 4;
    u16* yo = dir ? y1 : y0;

    {   // stage h_in (p-major 64x64 -> padded rows)
        int g = tid * 16, p = g >> 6, n = g & 63;
        const u16* hg = hin + (size_t)blk * 4096 + g;
        *(uint4*)&hs[p * 72 + n]     = *(const uint4*)hg;
        *(uint4*)&hs[p * 72 + n + 8] = *(const uint4*)(hg + 8);
    }
    const int sl0 = tid >> 3, ng = (tid & 7) * 8;
    #pragma unroll
    for (int it = 0; it < 4; it++) {
        int sl = sl0 + it * 32;
        int s = c * QC + sl;
        int t = dir ? (L_ - 1 - s) : s;
        const u16* bcr = BCb + ((size_t)b * L_ + t) * 128 + 64 + ng;
        float sc = wout[dbh * 2048 + s];
        uint4 cv = *(const uint4*)bcr;
        float cf[8]; unpack8(cv, cf);
        float f[8] = {cf[0]*sc, cf[1]*sc, cf[2]*sc, cf[3]*sc, cf[4]*sc, cf[5]*sc, cf[6]*sc, cf[7]*sc};
        *(uint4*)&Csc[sl * 72 + ng] = pack8(f);
    }
    __syncthreads();
    f32x4 acc[2][4];
    #pragma unroll
    for (int ti = 0; ti < 2; ti++)
        #pragma unroll
        for (int pj = 0; pj < 4; pj++) acc[ti][pj] = (f32x4){0.f, 0.f, 0.f, 0.f};
    #pragma unroll
    for (int ks = 0; ks < 2; ks++) {
        bf16x8 a0 = *(const bf16x8*)&Csc[(w * 32 + lr) * 72 + ks * 32 + lq * 8];
        bf16x8 a1 = *(const bf16x8*)&Csc[(w * 32 + 16 + lr) * 72 + ks * 32 + lq * 8];
        #pragma unroll
        for (int pj = 0; pj < 4; pj++) {
            bf16x8 bb = *(const bf16x8*)&hs[(pj * 16 + lr) * 72 + ks * 32 + lq * 8];
            acc[0][pj] = __builtin_amdgcn_mfma_f32_16x16x32_bf16(a0, bb, acc[0][pj], 0, 0, 0);
            acc[1][pj] = __builtin_amdgcn_mfma_f32_16x16x32_bf16(a1, bb, acc[1][pj], 0, 0, 0);
        }
    }
    #pragma unroll
    for (int ti = 0; ti < 2; ti++)
        #pragma unroll
        for (int pj = 0; pj < 4; pj++)
            #pragma unroll
            for (int r = 0; r < 4; r++) {
                int t_l = w * 32 + ti * 16 + lq * 4 + r;
                int s = c * QC + t_l;
                int t = dir ? (L_ - 1 - s) : s;
                u16* yp = yo + ((size_t)b * L_ + t) * DIN + h * 64 + pj * 16 + lr;
                *yp = f2b(acc[ti][pj][r] + b2f(*yp));    // RMW own rows only — no races
            }
}

// ---------- gate + RMSNorm -> bf16 (shift folded into the y reads) ----------
__global__ __launch_bounds__(256) void k_gate(const u16* __restrict__ xs, const u16* __restrict__ zx,
                                              const u16* __restrict__ y0, const u16* __restrict__ y1,
                                              const float* __restrict__ Dd,
                                              const float* __restrict__ nw, u16* __restrict__ yn) {
    int row = blockIdx.x, tid = threadIdx.x;
    int t = row & (L_ - 1);
    __shared__ float red[4];
    size_t base = (size_t)row * DIN;
    uint4 xv = ((const uint4*)(xs + base))[tid];
    uint4 zv = ((const uint4*)(zx + (size_t)row * NPAD))[tid];
    uint4 zero4 = {0u, 0u, 0u, 0u};
    uint4 a0 = (t > 0)      ? ((const uint4*)(y0 + base - DIN))[tid] : zero4;   // y_fwd[t-1]
    uint4 a1 = (t < L_ - 1) ? ((const uint4*)(y1 + base + DIN))[tid] : zero4;   // y_bwd[t+1]
    float sD = Dd[(size_t)row * 32 + (tid >> 3)];
    float xf[8], zf[8], f0[8], f1[8];
    unpack8(xv, xf); unpack8(zv, zf); unpack8(a0, f0); unpack8(a1, f1);
    int d0 = tid * 8;
    float g[8]; float ss = 0.f;
    #pragma unroll
    for (int i = 0; i < 8; i++) {
        float yv = f0[i] + f1[i] + xf[i] * sD;
        float z = zf[i];
        float gg = yv * (z / (1.f + __expf(-z)));
        g[i] = gg; ss += gg * gg;
    }
    for (int o = 32; o; o >>= 1) ss += __shfl_down(ss, o);
    if ((tid & 63) == 0) red[tid >> 6] = ss;
    __syncthreads();
    float tot = red[0] + red[1] + red[2] + red[3];
    float r = rsqrtf(tot * (1.f / DIN) + EPS);
    float o8[8];
    #pragma unroll
    for (int i = 0; i < 8; i++) o8[i] = g[i] * r * nw[d0 + i];
    ((uint4*)(yn + base))[tid] = pack8(o8);
}

// ---------- workspace layout (bytes) ----------
#define OFF_U     ((size_t)0)                       // BL*DM bf16 (dead after GEMM1)
#define OFF_WIN   ((size_t)16777216)                // NPAD*DM bf16
#define OFF_WOUT  ((size_t)25690112)                // DM*DIN bf16
#define OFF_ZX    ((size_t)29884416)                // BL*NPAD bf16
#define OFF_XS    ((size_t)101187584)               // BL*DIN bf16
#define OFF_BC    ((size_t)134742016)               // BL*128 bf16 = 2 MB
#define OFF_DTA   ((size_t)138936320)               // (unused)
#define OFF_Y0    ((size_t)143130624)               // BL*DIN bf16
#define OFF_Y1    ((size_t)176685056)               // BL*DIN bf16
#define OFF_YN    ((size_t)210239488)               // BL*DIN bf16 (gate out); scb/h_in aliases earlier
// aliases inside dead OFF_U region:
#define OFF_WO2   OFF_U                             // 256*2048 f32 = 2 MB
#define OFF_DEC   (OFF_U + 2097152)                 // 4096 f32
#define OFF_FCB   (OFF_U + 2113536)                 // NH*DIN bf16 = 128 KB
#define OFF_DD    (OFF_U + 2244608)                 // BL*32 f32 = 1 MB
#define OFF_SCB   OFF_YN                            // 4096*4096 bf16 = 33.5 MB (S_c -> h_in in place; dead before k_gate writes yn)
// total 243,793,920 bytes

extern "C" void kernel_launch(void* const* d_in, const int* in_sizes, int n_in,
                              void* d_out, int out_size, void* d_ws, size_t ws_size,
                              hipStream_t stream) {
    const float* x       = (const float*)d_in[0];
    const float* ln_g    = (const float*)d_in[1];
    const float* ln_b    = (const float*)d_in[2];
    const float* W_in    = (const float*)d_in[3];
    const float* conv_w  = (const float*)d_in[4];
    const float* conv_b  = (const float*)d_in[5];
    const float* dt_bias = (const float*)d_in[6];
    const float* A_log   = (const float*)d_in[7];
    const float* fc_D_w  = (const float*)d_in[8];
    const float* Dv      = (const float*)d_in[9];
    const float* norm_w  = (const float*)d_in[10];
    const float* W_out   = (const float*)d_in[11];

    char* ws = (char*)d_ws;
    u16*   u_bf  = (u16*)(ws + OFF_U);
    u16*   winb  = (u16*)(ws + OFF_WIN);
    u16*   woutb = (u16*)(ws + OFF_WOUT);
    u16*   zx    = (u16*)(ws + OFF_ZX);
    u16*   xs    = (u16*)(ws + OFF_XS);
    u16*   BCb   = (u16*)(ws + OFF_BC);
    u16*   y0b   = (u16*)(ws + OFF_Y0);
    u16*   y1b   = (u16*)(ws + OFF_Y1);
    u16*   ynb   = (u16*)(ws + OFF_YN);
    float* wo2   = (float*)(ws + OFF_WO2);
    float* dec   = (float*)(ws + OFF_DEC);
    u16*   fcb   = (u16*)(ws + OFF_FCB);
    float* Dd    = (float*)(ws + OFF_DD);
    u16*   scb   = (u16*)(ws + OFF_SCB);

    k_cvt_win <<<(NPAD * DM) / 256, 256, 0, stream>>>(W_in, winb);
    k_cvt_wout<<<(DM * DIN) / 256, 256, 0, stream>>>(W_out, woutb);
    k_ln      <<<BL, 256, 0, stream>>>(x, ln_g, ln_b, u_bf);
    k_gemm256 <<<(NPAD / 256) * (BL / 256), 512, 0, stream>>>(u_bf, winb, DM, zx, NPAD);
    k_cvt_fcd <<<(NH * DIN) / 256, 256, 0, stream>>>(fc_D_w, fcb);
    k_conv    <<<dim3(CONV_DIM / 64, L_ / 256, B_), 256, 0, stream>>>(zx, conv_w, conv_b, xs, BCb);
    k_dproj   <<<BL / 32, 256, 0, stream>>>(xs, fcb, Dv, Dd);
    k_chunk   <<<4096, 256, 0, stream>>>(xs, BCb, zx, dt_bias, A_log, y0b, y1b, wo2, dec, scb);
    k_hscan   <<<256, 256, 0, stream>>>(dec, scb);
    k_inter   <<<4096, 256, 0, stream>>>(BCb, wo2, scb, y0b, y1b);
    k_gate    <<<BL, 256, 0, stream>>>(xs, zx, y0b, y1b, Dd, norm_w, ynb);
    k_gemm_bt <<<dim3(DM / 128, BL / 128), 256, 0, stream>>>(ynb, woutb, BL, DM, DIN, 0, nullptr, DM, (float*)d_out, x);
}

// Round 5
// 534.781 us; speedup vs baseline: 1.0209x; 1.0010x over previous
//
#include <hip/hip_runtime.h>
#include <stdint.h>

// ---- problem constants ----
#define B_   4
#define L_   2048
#define DM   1024
#define DIN  2048
#define NH   32
#define HD   64
#define DSTATE 64
#define DCONV  7
#define CONV_DIM 2176            // DIN + 2*DSTATE
#define DPROJ 4288               // 2*DIN + 2*DSTATE + 2*NH
#define NPAD 4352                // DPROJ padded to 128
#define BL   8192                // B_*L_
#define EPS  1e-5f
#define QC   128                 // scan chunk length
#define NCH  16                  // chunks per sequence

typedef unsigned short u16;
typedef unsigned int   u32;
typedef __bf16 bf16x8 __attribute__((ext_vector_type(8)));
typedef float  f32x4  __attribute__((ext_vector_type(4)));

__device__ __forceinline__ float b2f(u32 b) { return __uint_as_float(b << 16); }
__device__ __forceinline__ u16 f2b(float f) {
    u32 u = __float_as_uint(f);
    u32 r = (u + 0x7fffu + ((u >> 16) & 1u)) >> 16;
    return (u16)r;
}
__device__ __forceinline__ void unpack8(uint4 v, float* f) {
    f[0] = b2f(v.x & 0xffffu); f[1] = b2f(v.x >> 16);
    f[2] = b2f(v.y & 0xffffu); f[3] = b2f(v.y >> 16);
    f[4] = b2f(v.z & 0xffffu); f[5] = b2f(v.z >> 16);
    f[6] = b2f(v.w & 0xffffu); f[7] = b2f(v.w >> 16);
}
__device__ __forceinline__ uint4 pack8(const float* f) {
    uint4 v;
    v.x = (u32)f2b(f[0]) | ((u32)f2b(f[1]) << 16);
    v.y = (u32)f2b(f[2]) | ((u32)f2b(f[3]) << 16);
    v.z = (u32)f2b(f[4]) | ((u32)f2b(f[5]) << 16);
    v.w = (u32)f2b(f[6]) | ((u32)f2b(f[7]) << 16);
    return v;
}
// skewed LDS index for transposed tiles: row-stride 136 u16 + 8-u16 skew per 8 rows.
__device__ __forceinline__ int xts(int p, int s) { return p * 136 + ((p >> 3) << 3) + s; }
// async global->LDS, 16B per lane; lds base must be wave-uniform (HW adds lane*16)
__device__ __forceinline__ void gload_lds16(const u16* g, u16* l) {
    __builtin_amdgcn_global_load_lds((const __attribute__((address_space(1))) void*)g,
                                     (__attribute__((address_space(3))) void*)l, 16, 0, 0);
}

// ---------- weight conversion ----------
__global__ __launch_bounds__(256) void k_cvt_win(const float* __restrict__ W, u16* __restrict__ Wb) {
    int idx = blockIdx.x * 256 + threadIdx.x;      // over NPAD*DM
    int n = idx >> 10;                              // DM = 1024
    float v = (n < DPROJ) ? W[(size_t)n * DM + (idx & 1023)] : 0.f;
    Wb[idx] = f2b(v);
}
__global__ __launch_bounds__(256) void k_cvt_wout(const float* __restrict__ W, u16* __restrict__ Wb) {
    int idx = blockIdx.x * 256 + threadIdx.x;      // over DM*DIN
    Wb[idx] = f2b(W[idx]);
}
__global__ __launch_bounds__(256) void k_cvt_fcd(const float* __restrict__ W, u16* __restrict__ Wb) {
    int idx = blockIdx.x * 256 + threadIdx.x;      // over NH*DIN
    Wb[idx] = f2b(W[idx]);
}

// ---------- layernorm -> bf16 ----------
__global__ __launch_bounds__(256) void k_ln(const float* __restrict__ x, const float* __restrict__ g,
                                            const float* __restrict__ be, u16* __restrict__ u) {
    int row = blockIdx.x, tid = threadIdx.x;
    const float4* xr = (const float4*)(x + (size_t)row * DM);
    float4 v = xr[tid];
    float s1 = v.x + v.y + v.z + v.w;
    float s2 = v.x * v.x + v.y * v.y + v.z * v.z + v.w * v.w;
    for (int o = 32; o; o >>= 1) { s1 += __shfl_down(s1, o); s2 += __shfl_down(s2, o); }
    __shared__ float ls1[4], ls2[4];
    int w = tid >> 6;
    if ((tid & 63) == 0) { ls1[w] = s1; ls2[w] = s2; }
    __syncthreads();
    float t1 = ls1[0] + ls1[1] + ls1[2] + ls1[3];
    float t2 = ls2[0] + ls2[1] + ls2[2] + ls2[3];
    float mu = t1 * (1.f / DM);
    float var = t2 * (1.f / DM) - mu * mu;
    float rs = rsqrtf(var + EPS);
    float4 gv = ((const float4*)g)[tid];
    float4 bv = ((const float4*)be)[tid];
    float o0 = (v.x - mu) * rs * gv.x + bv.x;
    float o1 = (v.y - mu) * rs * gv.y + bv.y;
    float o2 = (v.z - mu) * rs * gv.z + bv.z;
    float o3 = (v.w - mu) * rs * gv.w + bv.w;
    uint2 p;
    p.x = (u32)f2b(o0) | ((u32)f2b(o1) << 16);
    p.y = (u32)f2b(o2) | ((u32)f2b(o3) << 16);
    ((uint2*)(u + (size_t)row * DM))[tid] = p;
}

// ---------- bf16 MFMA GEMM, C[m,n] = sum_k A[m,k]*B[n,k]  (B^T layout) ----------
// 128x128 tile, 2-barrier K-loop, global_load_lds width=16 staging (proven m97
// structure; 95.4 us on GEMM1 here). 256^2 deep-pipeline variants tried in
// rounds 1-4 all regressed (103-120 us, MfmaUtil <30%) -- do not revisit
// without new evidence (e.g. inspectable m201 asm).
__global__ __launch_bounds__(256) void k_gemm_bt(const u16* __restrict__ A, const u16* __restrict__ Bw,
                                                 int M, int N, int K, int out_bf16,
                                                 u16* __restrict__ obf, int ldo,
                                                 float* __restrict__ ofp, const float* __restrict__ res) {
    __shared__ __align__(16) u16 As[128 * 64];
    __shared__ __align__(16) u16 Bs[128 * 64];
    int tid = threadIdx.x;
    int m0 = blockIdx.y * 128, n0 = blockIdx.x * 128;
    int w = tid >> 6, lane = tid & 63;
    int wm = (w >> 1) * 64, wn = (w & 1) * 64;
    int lr = lane & 15, lq = lane >> 4;

    f32x4 acc[4][4];
    #pragma unroll
    for (int i = 0; i < 4; i++)
        #pragma unroll
        for (int j = 0; j < 4; j++) acc[i][j] = (f32x4){0.f, 0.f, 0.f, 0.f};

    for (int kt = 0; kt < K; kt += 64) {
        #pragma unroll
        for (int it = 0; it < 4; it++) {
            int s_idx = it * 256 + tid;
            int row = s_idx >> 3;
            int kcg = (s_idx & 7) ^ (row & 7);            // swizzled source chunk
            u16* lbase_a = &As[(it * 256 + w * 64) * 8];  // wave-uniform
            u16* lbase_b = &Bs[(it * 256 + w * 64) * 8];
            gload_lds16(A + (size_t)(m0 + row) * K + kt + kcg * 8, lbase_a);
            gload_lds16(Bw + (size_t)(n0 + row) * K + kt + kcg * 8, lbase_b);
        }
        __syncthreads();
        #pragma unroll
        for (int kk = 0; kk < 2; kk++) {
            bf16x8 af[4], bfr[4];
            #pragma unroll
            for (int i = 0; i < 4; i++) {
                int row = wm + 16 * i + lr;
                af[i] = *(const bf16x8*)&As[row * 64 + (((kk * 4 + lq)) ^ (row & 7)) * 8];
            }
            #pragma unroll
            for (int j = 0; j < 4; j++) {
                int row = wn + 16 * j + lr;
                bfr[j] = *(const bf16x8*)&Bs[row * 64 + (((kk * 4 + lq)) ^ (row & 7)) * 8];
            }
            #pragma unroll
            for (int i = 0; i < 4; i++)
                #pragma unroll
                for (int j = 0; j < 4; j++)
                    acc[i][j] = __builtin_amdgcn_mfma_f32_16x16x32_bf16(af[i], bfr[j], acc[i][j], 0, 0, 0);
        }
        __syncthreads();
    }
    #pragma unroll
    for (int i = 0; i < 4; i++) {
        #pragma unroll
        for (int j = 0; j < 4; j++) {
            #pragma unroll
            for (int rr = 0; rr < 4; rr++) {
                int m = m0 + wm + 16 * i + lq * 4 + rr;
                int n = n0 + wn + 16 * j + lr;
                float v = acc[i][j][rr];
                if (out_bf16) obf[(size_t)m * ldo + n] = f2b(v);
                else          ofp[(size_t)m * ldo + n] = v + res[(size_t)m * ldo + n];
            }
        }
    }
}

// ---------- D-projection GEMM: Dd[m][h] = dot(xs[m,:], fc_D_w[h,:]) + Dv[h] ----------
__global__ __launch_bounds__(256) void k_dproj(const u16* __restrict__ xs, const u16* __restrict__ fcb,
                                               const float* __restrict__ Dv, float* __restrict__ Dd) {
    __shared__ __align__(16) u16 As[32 * 72];
    __shared__ __align__(16) u16 Bs[32 * 72];
    int tid = threadIdx.x;
    int m0 = blockIdx.x * 32;
    int w = tid >> 6, lane = tid & 63, lr = lane & 15, lq = lane >> 4;
    int mt = (w & 1) * 16, nt = (w >> 1) * 16;
    int r = tid >> 3, kc = tid & 7;
    f32x4 acc = (f32x4){0.f, 0.f, 0.f, 0.f};
    for (int kt = 0; kt < DIN; kt += 64) {
        *(uint4*)&As[r * 72 + kc * 8] = *(const uint4*)(xs + (size_t)(m0 + r) * DIN + kt + kc * 8);
        *(uint4*)&Bs[r * 72 + kc * 8] = *(const uint4*)(fcb + (size_t)r * DIN + kt + kc * 8);
        __syncthreads();
        #pragma unroll
        for (int ks = 0; ks < 2; ks++) {
            bf16x8 a = *(const bf16x8*)&As[(mt + lr) * 72 + ks * 32 + lq * 8];
            bf16x8 b = *(const bf16x8*)&Bs[(nt + lr) * 72 + ks * 32 + lq * 8];
            acc = __builtin_amdgcn_mfma_f32_16x16x32_bf16(a, b, acc, 0, 0, 0);
        }
        __syncthreads();
    }
    #pragma unroll
    for (int rr = 0; rr < 4; rr++) {
        int m = m0 + mt + lq * 4 + rr;
        int n = nt + lr;
        Dd[(size_t)m * 32 + n] = acc[rr] + Dv[n];
    }
}

// ---------- depthwise conv7 (same-pad) + bias + SiLU, split xs / BC(bf16) ----------
__global__ __launch_bounds__(256) void k_conv(const u16* __restrict__ zx, const float* __restrict__ cw,
                                              const float* __restrict__ cb, u16* __restrict__ xs,
                                              u16* __restrict__ BCb) {
    __shared__ u16 sh[262 * 64];
    int c0 = blockIdx.x * 64, t0 = blockIdx.y * 256, b = blockIdx.z;
    int tid = threadIdx.x;
    int c = tid & 63, tg = tid >> 6;
    for (int it = 0; it < 66; it++) {
        int r = it * 4 + tg;
        if (r < 262) {
            int t = t0 + r - 3;
            u16 v = 0;
            if (t >= 0 && t < L_) v = zx[(size_t)(b * L_ + t) * NPAD + DIN + c0 + c];
            sh[r * 64 + c] = v;
        }
    }
    float wgt[7];
    #pragma unroll
    for (int k = 0; k < 7; k++) wgt[k] = cw[(c0 + c) * 7 + k];
    float bias = cb[c0 + c];
    __syncthreads();
    int cg = c0 + c;
    for (int tt = 0; tt < 64; tt++) {
        int tl = tt * 4 + tg;
        float a = bias;
        #pragma unroll
        for (int k = 0; k < 7; k++) a += b2f(sh[(tl + k) * 64 + c]) * wgt[k];
        float v = a / (1.f + __expf(-a));   // silu
        size_t row = (size_t)b * L_ + (t0 + tl);
        if (cg < DIN) xs[row * DIN + cg] = f2b(v);
        else          BCb[row * 128 + (cg - DIN)] = f2b(v);   // B at [0,64), C at [64,128), bf16
    }
}

// ======================================================================
// Chunked SSD scan (intra-chunk + chunk-state + inline dt): block = (dir,b,h,chunk).
// ======================================================================
__global__ __launch_bounds__(256) void k_chunk(const u16* __restrict__ xs, const u16* __restrict__ BCb,
                                               const u16* __restrict__ zx, const float* __restrict__ dt_bias,
                                               const float* __restrict__ A_log, u16* __restrict__ y0,
                                               u16* __restrict__ y1, float* __restrict__ wout,
                                               float* __restrict__ decay, u16* __restrict__ scb) {
    __shared__ __align__(16) u16 ab[18432];      // Cs [0,9216) stride 72, Bs [9216,18432); S overlays (skewed 136)
    __shared__ __align__(16) u16 XT[8768];       // X^T [p][s] skewed
    __shared__ __align__(16) u16 BT[8768];       // B^T [n][s] skewed
    __shared__ __align__(16) float dts_s[128];
    __shared__ __align__(16) float lda_s[128];
    __shared__ __align__(16) float wend[128];
    __shared__ __align__(16) double cumd[128];

    const int blk = blockIdx.x;
    const int c = blk & 15, dbh = blk >> 4;
    const int h = dbh & 31, b = (dbh >> 5) & 3, dir = dbh >> 7;
    const int tid = threadIdx.x, w = tid >> 6, lane = tid & 63, lr = lane & 15, lq = lane >> 4;
    const int s0 = c * QC;
    u16* yo = dir ? y1 : y0;

    if (tid < 128) {   // inline dt2 / log-dA
        int s = s0 + tid;
        int t = dir ? (L_ - 1 - s) : s;
        float draw = b2f(zx[(size_t)(b * L_ + t) * NPAD + (DIN + CONV_DIM) + dir * 32 + h]);
        float xb = draw + dt_bias[h];
        float dt2 = (xb > 20.f) ? xb : log1pf(__expf(xb));
        dts_s[tid] = dt2;
        lda_s[tid] = -__expf(A_log[h]) * dt2;
    }
    {   // stage Cs, Bs (bf16 row-major), BT, XT (transposed, skewed)
        int sl0 = tid >> 3, ng = (tid & 7) * 8;
        #pragma unroll
        for (int it = 0; it < 4; it++) {
            int sl = sl0 + it * 32;
            int s = s0 + sl;
            int t = dir ? (L_ - 1 - s) : s;
            size_t row = (size_t)b * L_ + t;
            const u16* bcr = BCb + row * 128;
            uint4 cv = *(const uint4*)(bcr + 64 + ng);
            *(uint4*)&ab[sl * 72 + ng] = cv;
            uint4 pb = *(const uint4*)(bcr + ng);
            *(uint4*)&ab[9216 + sl * 72 + ng] = pb;
            u16 bh[8] = {(u16)(pb.x & 0xffffu), (u16)(pb.x >> 16), (u16)(pb.y & 0xffffu), (u16)(pb.y >> 16),
                         (u16)(pb.z & 0xffffu), (u16)(pb.z >> 16), (u16)(pb.w & 0xffffu), (u16)(pb.w >> 16)};
            #pragma unroll
            for (int i = 0; i < 8; i++) BT[(ng + i) * 136 + ng + sl] = bh[i];   // skew = ng
            uint4 xv = *(const uint4*)(xs + row * DIN + h * 64 + ng);
            u16 xh[8] = {(u16)(xv.x & 0xffffu), (u16)(xv.x >> 16), (u16)(xv.y & 0xffffu), (u16)(xv.y >> 16),
                         (u16)(xv.z & 0xffffu), (u16)(xv.z >> 16), (u16)(xv.w & 0xffffu), (u16)(xv.w >> 16)};
            #pragma unroll
            for (int i = 0; i < 8; i++) XT[(ng + i) * 136 + ng + sl] = xh[i];   // skew = ng
        }
    }
    __syncthreads();
    if (w == 0) {   // double-precision inclusive prefix of log-dA (wave 0)
        double v0 = (double)lda_s[lane];
        double v1 = (double)lda_s[64 + lane];
        #pragma unroll
        for (int o = 1; o < 64; o <<= 1) {
            double t0 = __shfl_up(v0, o);
            double t1 = __shfl_up(v1, o);
            if (lane >= o) { v0 += t0; v1 += t1; }
        }
        double tot0 = __shfl(v0, 63);
        cumd[lane] = v0;
        cumd[64 + lane] = tot0 + v1;
    }
    // G = C * B^T  (wave w owns t-rows [w*32, w*32+32))
    bf16x8 af[2][2];
    #pragma unroll
    for (int ti = 0; ti < 2; ti++)
        #pragma unroll
        for (int ks = 0; ks < 2; ks++)
            af[ti][ks] = *(const bf16x8*)&ab[(w * 32 + ti * 16 + lr) * 72 + ks * 32 + lq * 8];
    f32x4 accg[2][8];
    #pragma unroll
    for (int ti = 0; ti < 2; ti++)
        #pragma unroll
        for (int si = 0; si < 8; si++) accg[ti][si] = (f32x4){0.f, 0.f, 0.f, 0.f};
    #pragma unroll
    for (int si = 0; si < 8; si++)
        #pragma unroll
        for (int ks = 0; ks < 2; ks++) {
            bf16x8 bf = *(const bf16x8*)&ab[9216 + (si * 16 + lr) * 72 + ks * 32 + lq * 8];
            accg[0][si] = __builtin_amdgcn_mfma_f32_16x16x32_bf16(af[0][ks], bf, accg[0][si], 0, 0, 0);
            accg[1][si] = __builtin_amdgcn_mfma_f32_16x16x32_bf16(af[1][ks], bf, accg[1][si], 0, 0, 0);
        }
    __syncthreads();   // all G frag reads done; cumd ready
    // wend[s] = exp(cum[127]-cum[s])*dt[s]  (for chunk-state); visible after next barrier
    if (tid < 128) wend[tid] = __expf((float)(cumd[127] - cumd[tid])) * dts_s[tid];
    // S = M .* G  -> overlay into ab (skewed stride 136)
    {
        double cumt_d[8];
        #pragma unroll
        for (int ti = 0; ti < 2; ti++)
            #pragma unroll
            for (int r = 0; r < 4; r++) cumt_d[ti * 4 + r] = cumd[w * 32 + ti * 16 + lq * 4 + r];
        double cums_d[8]; float dts_l[8];
        #pragma unroll
        for (int si = 0; si < 8; si++) { cums_d[si] = cumd[si * 16 + lr]; dts_l[si] = dts_s[si * 16 + lr]; }
        #pragma unroll
        for (int ti = 0; ti < 2; ti++)
            #pragma unroll
            for (int si = 0; si < 8; si++)
                #pragma unroll
                for (int r = 0; r < 4; r++) {
                    int t_l = w * 32 + ti * 16 + lq * 4 + r;
                    int s_l = si * 16 + lr;
                    float v = 0.f;
                    if (s_l <= t_l)
                        v = __expf((float)(cumt_d[ti * 4 + r] - cums_d[si])) * dts_l[si] * accg[ti][si][r];
                    ab[xts(t_l, s_l)] = f2b(v);
                }
    }
    __syncthreads();
    // Y_intra = S * X^T
    f32x4 acc[2][4];
    #pragma unroll
    for (int ti = 0; ti < 2; ti++)
        #pragma unroll
        for (int pj = 0; pj < 4; pj++) acc[ti][pj] = (f32x4){0.f, 0.f, 0.f, 0.f};
    #pragma unroll
    for (int ks = 0; ks < 4; ks++) {
        bf16x8 a0 = *(const bf16x8*)&ab[xts(w * 32 + lr, ks * 32 + lq * 8)];
        bf16x8 a1 = *(const bf16x8*)&ab[xts(w * 32 + 16 + lr, ks * 32 + lq * 8)];
        #pragma unroll
        for (int pj = 0; pj < 4; pj++) {
            bf16x8 bf = *(const bf16x8*)&XT[xts(pj * 16 + lr, ks * 32 + lq * 8)];
            acc[0][pj] = __builtin_amdgcn_mfma_f32_16x16x32_bf16(a0, bf, acc[0][pj], 0, 0, 0);
            acc[1][pj] = __builtin_amdgcn_mfma_f32_16x16x32_bf16(a1, bf, acc[1][pj], 0, 0, 0);
        }
    }
    #pragma unroll
    for (int ti = 0; ti < 2; ti++)
        #pragma unroll
        for (int pj = 0; pj < 4; pj++)
            #pragma unroll
            for (int r = 0; r < 4; r++) {
                int t_l = w * 32 + ti * 16 + lq * 4 + r;
                int s = s0 + t_l;
                int t = dir ? (L_ - 1 - s) : s;
                yo[((size_t)b * L_ + t) * DIN + h * 64 + pj * 16 + lr] = f2b(acc[ti][pj][r]);
            }
    // chunk state S_c[p][n] = sum_s wend[s]*x[s][p]*B[s][n]
    f32x4 accs[4];
    #pragma unroll
    for (int nj = 0; nj < 4; nj++) accs[nj] = (f32x4){0.f, 0.f, 0.f, 0.f};
    #pragma unroll
    for (int ks = 0; ks < 4; ks++) {
        uint4 xv = *(const uint4*)&XT[xts(w * 16 + lr, ks * 32 + lq * 8)];
        float xf[8]; unpack8(xv, xf);
        float4 w0 = *(const float4*)&wend[ks * 32 + lq * 8];
        float4 w1 = *(const float4*)&wend[ks * 32 + lq * 8 + 4];
        float fs[8] = {xf[0]*w0.x, xf[1]*w0.y, xf[2]*w0.z, xf[3]*w0.w,
                       xf[4]*w1.x, xf[5]*w1.y, xf[6]*w1.z, xf[7]*w1.w};
        bf16x8 a = __builtin_bit_cast(bf16x8, pack8(fs));
        #pragma unroll
        for (int nj = 0; nj < 4; nj++) {
            bf16x8 bb = *(const bf16x8*)&BT[xts(nj * 16 + lr, ks * 32 + lq * 8)];
            accs[nj] = __builtin_amdgcn_mfma_f32_16x16x32_bf16(a, bb, accs[nj], 0, 0, 0);
        }
    }
    #pragma unroll
    for (int nj = 0; nj < 4; nj++)
        #pragma unroll
        for (int r = 0; r < 4; r++) {
            int p = w * 16 + lq * 4 + r, n = nj * 16 + lr;
            scb[(size_t)blk * 4096 + p * 64 + n] = f2b(accs[nj][r]);
        }
    if (tid < 128) wout[dbh * 2048 + s0 + tid] = __expf((float)cumd[tid]);
    if (tid == 0)  decay[blk] = __expf((float)cumd[127]);
}

// ---------- h-state scan (barrier-free): rewrites scb slots in place with h_in per chunk ----------
// elementwise recurrence h = decay*h + S_c over 16 chunks; split the 4096-slot
// (p,n) space across 4 blocks per dbh (1024 blocks total) for 4x the TLP of
// the old 256-block version (1/CU, latency-bound). Each thread owns 4 slots.
__global__ __launch_bounds__(256) void k_hscan(const float* __restrict__ decay, u16* __restrict__ scb) {
    int bid = blockIdx.x;                 // 1024 = 256 dbh x 4 slices
    int dbh = bid >> 2, ps = bid & 3;
    int tid = threadIdx.x;
    u16* base = scb + (size_t)dbh * 16 * 4096 + ps * 1024 + tid * 4;
    float h0 = 0.f, h1 = 0.f, h2 = 0.f, h3 = 0.f;
    for (int c = 0; c < NCH; c++) {
        u16* sg = base + (size_t)c * 4096;
        uint2 q = *(const uint2*)sg;
        float s0 = b2f(q.x & 0xffffu), s1 = b2f(q.x >> 16);
        float s2 = b2f(q.y & 0xffffu), s3 = b2f(q.y >> 16);
        uint2 o;
        o.x = (u32)f2b(h0) | ((u32)f2b(h1) << 16);
        o.y = (u32)f2b(h2) | ((u32)f2b(h3) << 16);
        *(uint2*)sg = o;                  // h entering chunk c
        float dk = decay[dbh * 16 + c];
        h0 = dk * h0 + s0; h1 = dk * h1 + s1;
        h2 = dk * h2 + s2; h3 = dk * h3 + s3;
    }
}

// ---------- inter-chunk contribution (parallel): y += (wout.*C) * h_in^T ----------
__global__ __launch_bounds__(256) void k_inter(const u16* __restrict__ BCb, const float* __restrict__ wout,
                                               const u16* __restrict__ hin, u16* __restrict__ y0,
                                               u16* __restrict__ y1) {
    __shared__ __align__(16) u16 Csc[128 * 72];      // wout[s]*C[s][n]
    __shared__ __align__(16) u16 hs[64 * 72];        // h_in[p][n], padded
    const int blk = blockIdx.x;
    const int c = blk & 15, dbh = blk >> 4;
    const int h = dbh & 31, b = (dbh >> 5) & 3, dir = dbh >> 7;
    const int tid = threadIdx.x, w = tid >> 6, lane = tid & 63, lr = lane & 15, lq = lane >> 4;
    u16* yo = dir ? y1 : y0;

    {   // stage h_in (p-major 64x64 -> padded rows)
        int g = tid * 16, p = g >> 6, n = g & 63;
        const u16* hg = hin + (size_t)blk * 4096 + g;
        *(uint4*)&hs[p * 72 + n]     = *(const uint4*)hg;
        *(uint4*)&hs[p * 72 + n + 8] = *(const uint4*)(hg + 8);
    }
    const int sl0 = tid >> 3, ng = (tid & 7) * 8;
    #pragma unroll
    for (int it = 0; it < 4; it++) {
        int sl = sl0 + it * 32;
        int s = c * QC + sl;
        int t = dir ? (L_ - 1 - s) : s;
        const u16* bcr = BCb + ((size_t)b * L_ + t) * 128 + 64 + ng;
        float sc = wout[dbh * 2048 + s];
        uint4 cv = *(const uint4*)bcr;
        float cf[8]; unpack8(cv, cf);
        float f[8] = {cf[0]*sc, cf[1]*sc, cf[2]*sc, cf[3]*sc, cf[4]*sc, cf[5]*sc, cf[6]*sc, cf[7]*sc};
        *(uint4*)&Csc[sl * 72 + ng] = pack8(f);
    }
    __syncthreads();
    f32x4 acc[2][4];
    #pragma unroll
    for (int ti = 0; ti < 2; ti++)
        #pragma unroll
        for (int pj = 0; pj < 4; pj++) acc[ti][pj] = (f32x4){0.f, 0.f, 0.f, 0.f};
    #pragma unroll
    for (int ks = 0; ks < 2; ks++) {
        bf16x8 a0 = *(const bf16x8*)&Csc[(w * 32 + lr) * 72 + ks * 32 + lq * 8];
        bf16x8 a1 = *(const bf16x8*)&Csc[(w * 32 + 16 + lr) * 72 + ks * 32 + lq * 8];
        #pragma unroll
        for (int pj = 0; pj < 4; pj++) {
            bf16x8 bb = *(const bf16x8*)&hs[(pj * 16 + lr) * 72 + ks * 32 + lq * 8];
            acc[0][pj] = __builtin_amdgcn_mfma_f32_16x16x32_bf16(a0, bb, acc[0][pj], 0, 0, 0);
            acc[1][pj] = __builtin_amdgcn_mfma_f32_16x16x32_bf16(a1, bb, acc[1][pj], 0, 0, 0);
        }
    }
    #pragma unroll
    for (int ti = 0; ti < 2; ti++)
        #pragma unroll
        for (int pj = 0; pj < 4; pj++)
            #pragma unroll
            for (int r = 0; r < 4; r++) {
                int t_l = w * 32 + ti * 16 + lq * 4 + r;
                int s = c * QC + t_l;
                int t = dir ? (L_ - 1 - s) : s;
                u16* yp = yo + ((size_t)b * L_ + t) * DIN + h * 64 + pj * 16 + lr;
                *yp = f2b(acc[ti][pj][r] + b2f(*yp));    // RMW own rows only — no races
            }
}

// ---------- gate + RMSNorm -> bf16 (shift folded into the y reads) ----------
__global__ __launch_bounds__(256) void k_gate(const u16* __restrict__ xs, const u16* __restrict__ zx,
                                              const u16* __restrict__ y0, const u16* __restrict__ y1,
                                              const float* __restrict__ Dd,
                                              const float* __restrict__ nw, u16* __restrict__ yn) {
    int row = blockIdx.x, tid = threadIdx.x;
    int t = row & (L_ - 1);
    __shared__ float red[4];
    size_t base = (size_t)row * DIN;
    uint4 xv = ((const uint4*)(xs + base))[tid];
    uint4 zv = ((const uint4*)(zx + (size_t)row * NPAD))[tid];
    uint4 zero4 = {0u, 0u, 0u, 0u};
    uint4 a0 = (t > 0)      ? ((const uint4*)(y0 + base - DIN))[tid] : zero4;   // y_fwd[t-1]
    uint4 a1 = (t < L_ - 1) ? ((const uint4*)(y1 + base + DIN))[tid] : zero4;   // y_bwd[t+1]
    float sD = Dd[(size_t)row * 32 + (tid >> 3)];
    float xf[8], zf[8], f0[8], f1[8];
    unpack8(xv, xf); unpack8(zv, zf); unpack8(a0, f0); unpack8(a1, f1);
    int d0 = tid * 8;
    float g[8]; float ss = 0.f;
    #pragma unroll
    for (int i = 0; i < 8; i++) {
        float yv = f0[i] + f1[i] + xf[i] * sD;
        float z = zf[i];
        float gg = yv * (z / (1.f + __expf(-z)));
        g[i] = gg; ss += gg * gg;
    }
    for (int o = 32; o; o >>= 1) ss += __shfl_down(ss, o);
    if ((tid & 63) == 0) red[tid >> 6] = ss;
    __syncthreads();
    float tot = red[0] + red[1] + red[2] + red[3];
    float r = rsqrtf(tot * (1.f / DIN) + EPS);
    float o8[8];
    #pragma unroll
    for (int i = 0; i < 8; i++) o8[i] = g[i] * r * nw[d0 + i];
    ((uint4*)(yn + base))[tid] = pack8(o8);
}

// ---------- workspace layout (bytes) ----------
#define OFF_U     ((size_t)0)                       // BL*DM bf16 (dead after GEMM1)
#define OFF_WIN   ((size_t)16777216)                // NPAD*DM bf16
#define OFF_WOUT  ((size_t)25690112)                // DM*DIN bf16
#define OFF_ZX    ((size_t)29884416)                // BL*NPAD bf16
#define OFF_XS    ((size_t)101187584)               // BL*DIN bf16
#define OFF_BC    ((size_t)134742016)               // BL*128 bf16 = 2 MB
#define OFF_DTA   ((size_t)138936320)               // (unused)
#define OFF_Y0    ((size_t)143130624)               // BL*DIN bf16
#define OFF_Y1    ((size_t)176685056)               // BL*DIN bf16
#define OFF_YN    ((size_t)210239488)               // BL*DIN bf16 (gate out); scb/h_in aliases earlier
// aliases inside dead OFF_U region:
#define OFF_WO2   OFF_U                             // 256*2048 f32 = 2 MB
#define OFF_DEC   (OFF_U + 2097152)                 // 4096 f32
#define OFF_FCB   (OFF_U + 2113536)                 // NH*DIN bf16 = 128 KB
#define OFF_DD    (OFF_U + 2244608)                 // BL*32 f32 = 1 MB
#define OFF_SCB   OFF_YN                            // 4096*4096 bf16 = 33.5 MB (S_c -> h_in in place; dead before k_gate writes yn)
// total 243,793,920 bytes

extern "C" void kernel_launch(void* const* d_in, const int* in_sizes, int n_in,
                              void* d_out, int out_size, void* d_ws, size_t ws_size,
                              hipStream_t stream) {
    const float* x       = (const float*)d_in[0];
    const float* ln_g    = (const float*)d_in[1];
    const float* ln_b    = (const float*)d_in[2];
    const float* W_in    = (const float*)d_in[3];
    const float* conv_w  = (const float*)d_in[4];
    const float* conv_b  = (const float*)d_in[5];
    const float* dt_bias = (const float*)d_in[6];
    const float* A_log   = (const float*)d_in[7];
    const float* fc_D_w  = (const float*)d_in[8];
    const float* Dv      = (const float*)d_in[9];
    const float* norm_w  = (const float*)d_in[10];
    const float* W_out   = (const float*)d_in[11];

    char* ws = (char*)d_ws;
    u16*   u_bf  = (u16*)(ws + OFF_U);
    u16*   winb  = (u16*)(ws + OFF_WIN);
    u16*   woutb = (u16*)(ws + OFF_WOUT);
    u16*   zx    = (u16*)(ws + OFF_ZX);
    u16*   xs    = (u16*)(ws + OFF_XS);
    u16*   BCb   = (u16*)(ws + OFF_BC);
    u16*   y0b   = (u16*)(ws + OFF_Y0);
    u16*   y1b   = (u16*)(ws + OFF_Y1);
    u16*   ynb   = (u16*)(ws + OFF_YN);
    float* wo2   = (float*)(ws + OFF_WO2);
    float* dec   = (float*)(ws + OFF_DEC);
    u16*   fcb   = (u16*)(ws + OFF_FCB);
    float* Dd    = (float*)(ws + OFF_DD);
    u16*   scb   = (u16*)(ws + OFF_SCB);

    k_cvt_win <<<(NPAD * DM) / 256, 256, 0, stream>>>(W_in, winb);
    k_cvt_wout<<<(DM * DIN) / 256, 256, 0, stream>>>(W_out, woutb);
    k_ln      <<<BL, 256, 0, stream>>>(x, ln_g, ln_b, u_bf);
    k_gemm_bt <<<dim3(NPAD / 128, BL / 128), 256, 0, stream>>>(u_bf, winb, BL, NPAD, DM, 1, zx, NPAD, nullptr, nullptr);
    k_cvt_fcd <<<(NH * DIN) / 256, 256, 0, stream>>>(fc_D_w, fcb);
    k_conv    <<<dim3(CONV_DIM / 64, L_ / 256, B_), 256, 0, stream>>>(zx, conv_w, conv_b, xs, BCb);
    k_dproj   <<<BL / 32, 256, 0, stream>>>(xs, fcb, Dv, Dd);
    k_chunk   <<<4096, 256, 0, stream>>>(xs, BCb, zx, dt_bias, A_log, y0b, y1b, wo2, dec, scb);
    k_hscan   <<<1024, 256, 0, stream>>>(dec, scb);
    k_inter   <<<4096, 256, 0, stream>>>(BCb, wo2, scb, y0b, y1b);
    k_gate    <<<BL, 256, 0, stream>>>(xs, zx, y0b, y1b, Dd, norm_w, ynb);
    k_gemm_bt <<<dim3(DM / 128, BL / 128), 256, 0, stream>>>(ynb, woutb, BL, DM, DIN, 0, nullptr, DM, (float*)d_out, x);
}

// Round 6
// 520.648 us; speedup vs baseline: 1.0486x; 1.0271x over previous
//
#include <hip/hip_runtime.h>
#include <stdint.h>

// ---- problem constants ----
#define B_   4
#define L_   2048
#define DM   1024
#define DIN  2048
#define NH   32
#define HD   64
#define DSTATE 64
#define DCONV  7
#define CONV_DIM 2176            // DIN + 2*DSTATE
#define DPROJ 4288               // 2*DIN + 2*DSTATE + 2*NH
#define NPAD 4352                // DPROJ padded to 128
#define BL   8192                // B_*L_
#define EPS  1e-5f
#define QC   128                 // scan chunk length
#define NCH  16                  // chunks per sequence

typedef unsigned short u16;
typedef unsigned int   u32;
typedef __bf16 bf16x8 __attribute__((ext_vector_type(8)));
typedef float  f32x4  __attribute__((ext_vector_type(4)));

__device__ __forceinline__ float b2f(u32 b) { return __uint_as_float(b << 16); }
__device__ __forceinline__ u16 f2b(float f) {
    u32 u = __float_as_uint(f);
    u32 r = (u + 0x7fffu + ((u >> 16) & 1u)) >> 16;
    return (u16)r;
}
__device__ __forceinline__ void unpack8(uint4 v, float* f) {
    f[0] = b2f(v.x & 0xffffu); f[1] = b2f(v.x >> 16);
    f[2] = b2f(v.y & 0xffffu); f[3] = b2f(v.y >> 16);
    f[4] = b2f(v.z & 0xffffu); f[5] = b2f(v.z >> 16);
    f[6] = b2f(v.w & 0xffffu); f[7] = b2f(v.w >> 16);
}
__device__ __forceinline__ uint4 pack8(const float* f) {
    uint4 v;
    v.x = (u32)f2b(f[0]) | ((u32)f2b(f[1]) << 16);
    v.y = (u32)f2b(f[2]) | ((u32)f2b(f[3]) << 16);
    v.z = (u32)f2b(f[4]) | ((u32)f2b(f[5]) << 16);
    v.w = (u32)f2b(f[6]) | ((u32)f2b(f[7]) << 16);
    return v;
}
// skewed LDS index for transposed tiles: row-stride 136 u16 + 8-u16 skew per 8 rows.
__device__ __forceinline__ int xts(int p, int s) { return p * 136 + ((p >> 3) << 3) + s; }
// async global->LDS, 16B per lane; lds base must be wave-uniform (HW adds lane*16)
__device__ __forceinline__ void gload_lds16(const u16* g, u16* l) {
    __builtin_amdgcn_global_load_lds((const __attribute__((address_space(1))) void*)g,
                                     (__attribute__((address_space(3))) void*)l, 16, 0, 0);
}

// ---------- weight conversion ----------
__global__ __launch_bounds__(256) void k_cvt_win(const float* __restrict__ W, u16* __restrict__ Wb) {
    int idx = blockIdx.x * 256 + threadIdx.x;      // over NPAD*DM
    int n = idx >> 10;                              // DM = 1024
    float v = (n < DPROJ) ? W[(size_t)n * DM + (idx & 1023)] : 0.f;
    Wb[idx] = f2b(v);
}
__global__ __launch_bounds__(256) void k_cvt_wout(const float* __restrict__ W, u16* __restrict__ Wb) {
    int idx = blockIdx.x * 256 + threadIdx.x;      // over DM*DIN
    Wb[idx] = f2b(W[idx]);
}
__global__ __launch_bounds__(256) void k_cvt_fcd(const float* __restrict__ W, u16* __restrict__ Wb) {
    int idx = blockIdx.x * 256 + threadIdx.x;      // over NH*DIN
    Wb[idx] = f2b(W[idx]);
}

// ---------- layernorm -> bf16 ----------
__global__ __launch_bounds__(256) void k_ln(const float* __restrict__ x, const float* __restrict__ g,
                                            const float* __restrict__ be, u16* __restrict__ u) {
    int row = blockIdx.x, tid = threadIdx.x;
    const float4* xr = (const float4*)(x + (size_t)row * DM);
    float4 v = xr[tid];
    float s1 = v.x + v.y + v.z + v.w;
    float s2 = v.x * v.x + v.y * v.y + v.z * v.z + v.w * v.w;
    for (int o = 32; o; o >>= 1) { s1 += __shfl_down(s1, o); s2 += __shfl_down(s2, o); }
    __shared__ float ls1[4], ls2[4];
    int w = tid >> 6;
    if ((tid & 63) == 0) { ls1[w] = s1; ls2[w] = s2; }
    __syncthreads();
    float t1 = ls1[0] + ls1[1] + ls1[2] + ls1[3];
    float t2 = ls2[0] + ls2[1] + ls2[2] + ls2[3];
    float mu = t1 * (1.f / DM);
    float var = t2 * (1.f / DM) - mu * mu;
    float rs = rsqrtf(var + EPS);
    float4 gv = ((const float4*)g)[tid];
    float4 bv = ((const float4*)be)[tid];
    float o0 = (v.x - mu) * rs * gv.x + bv.x;
    float o1 = (v.y - mu) * rs * gv.y + bv.y;
    float o2 = (v.z - mu) * rs * gv.z + bv.z;
    float o3 = (v.w - mu) * rs * gv.w + bv.w;
    uint2 p;
    p.x = (u32)f2b(o0) | ((u32)f2b(o1) << 16);
    p.y = (u32)f2b(o2) | ((u32)f2b(o3) << 16);
    ((uint2*)(u + (size_t)row * DM))[tid] = p;
}

// ---------- bf16 MFMA GEMM, C[m,n] = sum_k A[m,k]*B[n,k]  (B^T layout) ----------
// 128x128 tile, 2-barrier K-loop, global_load_lds width=16 staging (proven m97
// structure). 256^2 deep-pipeline variants tried in rounds 1-4 all regressed
// (103-120 us, MfmaUtil <30%) -- do not revisit without new evidence.
// NOTE: identical code measured 95.4 us (r0) vs ~112 us (r5) on different
// acquisitions -- cross-acquisition noise is ~+/-10%.
__global__ __launch_bounds__(256) void k_gemm_bt(const u16* __restrict__ A, const u16* __restrict__ Bw,
                                                 int M, int N, int K, int out_bf16,
                                                 u16* __restrict__ obf, int ldo,
                                                 float* __restrict__ ofp, const float* __restrict__ res) {
    __shared__ __align__(16) u16 As[128 * 64];
    __shared__ __align__(16) u16 Bs[128 * 64];
    int tid = threadIdx.x;
    int m0 = blockIdx.y * 128, n0 = blockIdx.x * 128;
    int w = tid >> 6, lane = tid & 63;
    int wm = (w >> 1) * 64, wn = (w & 1) * 64;
    int lr = lane & 15, lq = lane >> 4;

    f32x4 acc[4][4];
    #pragma unroll
    for (int i = 0; i < 4; i++)
        #pragma unroll
        for (int j = 0; j < 4; j++) acc[i][j] = (f32x4){0.f, 0.f, 0.f, 0.f};

    for (int kt = 0; kt < K; kt += 64) {
        #pragma unroll
        for (int it = 0; it < 4; it++) {
            int s_idx = it * 256 + tid;
            int row = s_idx >> 3;
            int kcg = (s_idx & 7) ^ (row & 7);            // swizzled source chunk
            u16* lbase_a = &As[(it * 256 + w * 64) * 8];  // wave-uniform
            u16* lbase_b = &Bs[(it * 256 + w * 64) * 8];
            gload_lds16(A + (size_t)(m0 + row) * K + kt + kcg * 8, lbase_a);
            gload_lds16(Bw + (size_t)(n0 + row) * K + kt + kcg * 8, lbase_b);
        }
        __syncthreads();
        #pragma unroll
        for (int kk = 0; kk < 2; kk++) {
            bf16x8 af[4], bfr[4];
            #pragma unroll
            for (int i = 0; i < 4; i++) {
                int row = wm + 16 * i + lr;
                af[i] = *(const bf16x8*)&As[row * 64 + (((kk * 4 + lq)) ^ (row & 7)) * 8];
            }
            #pragma unroll
            for (int j = 0; j < 4; j++) {
                int row = wn + 16 * j + lr;
                bfr[j] = *(const bf16x8*)&Bs[row * 64 + (((kk * 4 + lq)) ^ (row & 7)) * 8];
            }
            #pragma unroll
            for (int i = 0; i < 4; i++)
                #pragma unroll
                for (int j = 0; j < 4; j++)
                    acc[i][j] = __builtin_amdgcn_mfma_f32_16x16x32_bf16(af[i], bfr[j], acc[i][j], 0, 0, 0);
        }
        __syncthreads();
    }
    #pragma unroll
    for (int i = 0; i < 4; i++) {
        #pragma unroll
        for (int j = 0; j < 4; j++) {
            #pragma unroll
            for (int rr = 0; rr < 4; rr++) {
                int m = m0 + wm + 16 * i + lq * 4 + rr;
                int n = n0 + wn + 16 * j + lr;
                float v = acc[i][j][rr];
                if (out_bf16) obf[(size_t)m * ldo + n] = f2b(v);
                else          ofp[(size_t)m * ldo + n] = v + res[(size_t)m * ldo + n];
            }
        }
    }
}

// ---------- D-projection GEMM: Dd[m][h] = dot(xs[m,:], fc_D_w[h,:]) + Dv[h] ----------
__global__ __launch_bounds__(256) void k_dproj(const u16* __restrict__ xs, const u16* __restrict__ fcb,
                                               const float* __restrict__ Dv, float* __restrict__ Dd) {
    __shared__ __align__(16) u16 As[32 * 72];
    __shared__ __align__(16) u16 Bs[32 * 72];
    int tid = threadIdx.x;
    int m0 = blockIdx.x * 32;
    int w = tid >> 6, lane = tid & 63, lr = lane & 15, lq = lane >> 4;
    int mt = (w & 1) * 16, nt = (w >> 1) * 16;
    int r = tid >> 3, kc = tid & 7;
    f32x4 acc = (f32x4){0.f, 0.f, 0.f, 0.f};
    for (int kt = 0; kt < DIN; kt += 64) {
        *(uint4*)&As[r * 72 + kc * 8] = *(const uint4*)(xs + (size_t)(m0 + r) * DIN + kt + kc * 8);
        *(uint4*)&Bs[r * 72 + kc * 8] = *(const uint4*)(fcb + (size_t)r * DIN + kt + kc * 8);
        __syncthreads();
        #pragma unroll
        for (int ks = 0; ks < 2; ks++) {
            bf16x8 a = *(const bf16x8*)&As[(mt + lr) * 72 + ks * 32 + lq * 8];
            bf16x8 b = *(const bf16x8*)&Bs[(nt + lr) * 72 + ks * 32 + lq * 8];
            acc = __builtin_amdgcn_mfma_f32_16x16x32_bf16(a, b, acc, 0, 0, 0);
        }
        __syncthreads();
    }
    #pragma unroll
    for (int rr = 0; rr < 4; rr++) {
        int m = m0 + mt + lq * 4 + rr;
        int n = nt + lr;
        Dd[(size_t)m * 32 + n] = acc[rr] + Dv[n];
    }
}

// ---------- depthwise conv7 (same-pad) + bias + SiLU, split xs / BC(bf16) ----------
__global__ __launch_bounds__(256) void k_conv(const u16* __restrict__ zx, const float* __restrict__ cw,
                                              const float* __restrict__ cb, u16* __restrict__ xs,
                                              u16* __restrict__ BCb) {
    __shared__ u16 sh[262 * 64];
    int c0 = blockIdx.x * 64, t0 = blockIdx.y * 256, b = blockIdx.z;
    int tid = threadIdx.x;
    int c = tid & 63, tg = tid >> 6;
    for (int it = 0; it < 66; it++) {
        int r = it * 4 + tg;
        if (r < 262) {
            int t = t0 + r - 3;
            u16 v = 0;
            if (t >= 0 && t < L_) v = zx[(size_t)(b * L_ + t) * NPAD + DIN + c0 + c];
            sh[r * 64 + c] = v;
        }
    }
    float wgt[7];
    #pragma unroll
    for (int k = 0; k < 7; k++) wgt[k] = cw[(c0 + c) * 7 + k];
    float bias = cb[c0 + c];
    __syncthreads();
    int cg = c0 + c;
    for (int tt = 0; tt < 64; tt++) {
        int tl = tt * 4 + tg;
        float a = bias;
        #pragma unroll
        for (int k = 0; k < 7; k++) a += b2f(sh[(tl + k) * 64 + c]) * wgt[k];
        float v = a / (1.f + __expf(-a));   // silu
        size_t row = (size_t)b * L_ + (t0 + tl);
        if (cg < DIN) xs[row * DIN + cg] = f2b(v);
        else          BCb[row * 128 + (cg - DIN)] = f2b(v);   // B at [0,64), C at [64,128), bf16
    }
}

// ======================================================================
// Chunked SSD scan (intra-chunk + chunk-state + inline dt): block = (dir,b,h,chunk).
// R5: Y_intra and S_c outputs now staged through (dead) LDS regions and
// stored as coalesced uint4 (was 48 scalar 2B global stores per thread).
// Values bit-identical (same f2b(acc), just reordered through LDS).
// ======================================================================
__global__ __launch_bounds__(256) void k_chunk(const u16* __restrict__ xs, const u16* __restrict__ BCb,
                                               const u16* __restrict__ zx, const float* __restrict__ dt_bias,
                                               const float* __restrict__ A_log, u16* __restrict__ y0,
                                               u16* __restrict__ y1, float* __restrict__ wout,
                                               float* __restrict__ decay, u16* __restrict__ scb) {
    __shared__ __align__(16) u16 ab[18432];      // Cs [0,9216) stride 72, Bs [9216,18432); S overlays (skewed 136); y-stage overlays [t][72]
    __shared__ __align__(16) u16 XT[8768];       // X^T [p][s] skewed
    __shared__ __align__(16) u16 BT[8768];       // B^T [n][s] skewed; scb-stage overlays [p][72]
    __shared__ __align__(16) float dts_s[128];
    __shared__ __align__(16) float lda_s[128];
    __shared__ __align__(16) float wend[128];
    __shared__ __align__(16) double cumd[128];

    const int blk = blockIdx.x;
    const int c = blk & 15, dbh = blk >> 4;
    const int h = dbh & 31, b = (dbh >> 5) & 3, dir = dbh >> 7;
    const int tid = threadIdx.x, w = tid >> 6, lane = tid & 63, lr = lane & 15, lq = lane >> 4;
    const int s0 = c * QC;
    u16* yo = dir ? y1 : y0;

    if (tid < 128) {   // inline dt2 / log-dA
        int s = s0 + tid;
        int t = dir ? (L_ - 1 - s) : s;
        float draw = b2f(zx[(size_t)(b * L_ + t) * NPAD + (DIN + CONV_DIM) + dir * 32 + h]);
        float xb = draw + dt_bias[h];
        float dt2 = (xb > 20.f) ? xb : log1pf(__expf(xb));
        dts_s[tid] = dt2;
        lda_s[tid] = -__expf(A_log[h]) * dt2;
    }
    {   // stage Cs, Bs (bf16 row-major), BT, XT (transposed, skewed)
        int sl0 = tid >> 3, ng = (tid & 7) * 8;
        #pragma unroll
        for (int it = 0; it < 4; it++) {
            int sl = sl0 + it * 32;
            int s = s0 + sl;
            int t = dir ? (L_ - 1 - s) : s;
            size_t row = (size_t)b * L_ + t;
            const u16* bcr = BCb + row * 128;
            uint4 cv = *(const uint4*)(bcr + 64 + ng);
            *(uint4*)&ab[sl * 72 + ng] = cv;
            uint4 pb = *(const uint4*)(bcr + ng);
            *(uint4*)&ab[9216 + sl * 72 + ng] = pb;
            u16 bh[8] = {(u16)(pb.x & 0xffffu), (u16)(pb.x >> 16), (u16)(pb.y & 0xffffu), (u16)(pb.y >> 16),
                         (u16)(pb.z & 0xffffu), (u16)(pb.z >> 16), (u16)(pb.w & 0xffffu), (u16)(pb.w >> 16)};
            #pragma unroll
            for (int i = 0; i < 8; i++) BT[(ng + i) * 136 + ng + sl] = bh[i];   // skew = ng
            uint4 xv = *(const uint4*)(xs + row * DIN + h * 64 + ng);
            u16 xh[8] = {(u16)(xv.x & 0xffffu), (u16)(xv.x >> 16), (u16)(xv.y & 0xffffu), (u16)(xv.y >> 16),
                         (u16)(xv.z & 0xffffu), (u16)(xv.z >> 16), (u16)(xv.w & 0xffffu), (u16)(xv.w >> 16)};
            #pragma unroll
            for (int i = 0; i < 8; i++) XT[(ng + i) * 136 + ng + sl] = xh[i];   // skew = ng
        }
    }
    __syncthreads();
    if (w == 0) {   // double-precision inclusive prefix of log-dA (wave 0)
        double v0 = (double)lda_s[lane];
        double v1 = (double)lda_s[64 + lane];
        #pragma unroll
        for (int o = 1; o < 64; o <<= 1) {
            double t0 = __shfl_up(v0, o);
            double t1 = __shfl_up(v1, o);
            if (lane >= o) { v0 += t0; v1 += t1; }
        }
        double tot0 = __shfl(v0, 63);
        cumd[lane] = v0;
        cumd[64 + lane] = tot0 + v1;
    }
    // G = C * B^T  (wave w owns t-rows [w*32, w*32+32))
    bf16x8 af[2][2];
    #pragma unroll
    for (int ti = 0; ti < 2; ti++)
        #pragma unroll
        for (int ks = 0; ks < 2; ks++)
            af[ti][ks] = *(const bf16x8*)&ab[(w * 32 + ti * 16 + lr) * 72 + ks * 32 + lq * 8];
    f32x4 accg[2][8];
    #pragma unroll
    for (int ti = 0; ti < 2; ti++)
        #pragma unroll
        for (int si = 0; si < 8; si++) accg[ti][si] = (f32x4){0.f, 0.f, 0.f, 0.f};
    #pragma unroll
    for (int si = 0; si < 8; si++)
        #pragma unroll
        for (int ks = 0; ks < 2; ks++) {
            bf16x8 bf = *(const bf16x8*)&ab[9216 + (si * 16 + lr) * 72 + ks * 32 + lq * 8];
            accg[0][si] = __builtin_amdgcn_mfma_f32_16x16x32_bf16(af[0][ks], bf, accg[0][si], 0, 0, 0);
            accg[1][si] = __builtin_amdgcn_mfma_f32_16x16x32_bf16(af[1][ks], bf, accg[1][si], 0, 0, 0);
        }
    __syncthreads();   // all G frag reads done; cumd ready
    // wend[s] = exp(cum[127]-cum[s])*dt[s]  (for chunk-state); visible after next barrier
    if (tid < 128) wend[tid] = __expf((float)(cumd[127] - cumd[tid])) * dts_s[tid];
    // S = M .* G  -> overlay into ab (skewed stride 136)
    {
        double cumt_d[8];
        #pragma unroll
        for (int ti = 0; ti < 2; ti++)
            #pragma unroll
            for (int r = 0; r < 4; r++) cumt_d[ti * 4 + r] = cumd[w * 32 + ti * 16 + lq * 4 + r];
        double cums_d[8]; float dts_l[8];
        #pragma unroll
        for (int si = 0; si < 8; si++) { cums_d[si] = cumd[si * 16 + lr]; dts_l[si] = dts_s[si * 16 + lr]; }
        #pragma unroll
        for (int ti = 0; ti < 2; ti++)
            #pragma unroll
            for (int si = 0; si < 8; si++)
                #pragma unroll
                for (int r = 0; r < 4; r++) {
                    int t_l = w * 32 + ti * 16 + lq * 4 + r;
                    int s_l = si * 16 + lr;
                    float v = 0.f;
                    if (s_l <= t_l)
                        v = __expf((float)(cumt_d[ti * 4 + r] - cums_d[si])) * dts_l[si] * accg[ti][si][r];
                    ab[xts(t_l, s_l)] = f2b(v);
                }
    }
    __syncthreads();
    // Y_intra = S * X^T
    f32x4 acc[2][4];
    #pragma unroll
    for (int ti = 0; ti < 2; ti++)
        #pragma unroll
        for (int pj = 0; pj < 4; pj++) acc[ti][pj] = (f32x4){0.f, 0.f, 0.f, 0.f};
    #pragma unroll
    for (int ks = 0; ks < 4; ks++) {
        bf16x8 a0 = *(const bf16x8*)&ab[xts(w * 32 + lr, ks * 32 + lq * 8)];
        bf16x8 a1 = *(const bf16x8*)&ab[xts(w * 32 + 16 + lr, ks * 32 + lq * 8)];
        #pragma unroll
        for (int pj = 0; pj < 4; pj++) {
            bf16x8 bf = *(const bf16x8*)&XT[xts(pj * 16 + lr, ks * 32 + lq * 8)];
            acc[0][pj] = __builtin_amdgcn_mfma_f32_16x16x32_bf16(a0, bf, acc[0][pj], 0, 0, 0);
            acc[1][pj] = __builtin_amdgcn_mfma_f32_16x16x32_bf16(a1, bf, acc[1][pj], 0, 0, 0);
        }
    }
    // ---- Y_intra store: LDS-transpose (ab is dead after the barrier) then coalesced uint4 ----
    __syncthreads();                                 // all waves done reading S (ab)
    #pragma unroll
    for (int ti = 0; ti < 2; ti++)
        #pragma unroll
        for (int pj = 0; pj < 4; pj++)
            #pragma unroll
            for (int r = 0; r < 4; r++) {
                int t_l = w * 32 + ti * 16 + lq * 4 + r;
                ab[t_l * 72 + pj * 16 + lr] = f2b(acc[ti][pj][r]);   // [t][p] stride 72
            }
    __syncthreads();
    #pragma unroll
    for (int k2 = 0; k2 < 4; k2++) {
        int c2 = k2 * 256 + tid;
        int t_l = c2 >> 3, p0 = (c2 & 7) * 8;
        int s = s0 + t_l;
        int t = dir ? (L_ - 1 - s) : s;
        *(uint4*)(yo + ((size_t)b * L_ + t) * DIN + h * 64 + p0) = *(const uint4*)&ab[t_l * 72 + p0];
    }
    // chunk state S_c[p][n] = sum_s wend[s]*x[s][p]*B[s][n]
    f32x4 accs[4];
    #pragma unroll
    for (int nj = 0; nj < 4; nj++) accs[nj] = (f32x4){0.f, 0.f, 0.f, 0.f};
    #pragma unroll
    for (int ks = 0; ks < 4; ks++) {
        uint4 xv = *(const uint4*)&XT[xts(w * 16 + lr, ks * 32 + lq * 8)];
        float xf[8]; unpack8(xv, xf);
        float4 w0 = *(const float4*)&wend[ks * 32 + lq * 8];
        float4 w1 = *(const float4*)&wend[ks * 32 + lq * 8 + 4];
        float fs[8] = {xf[0]*w0.x, xf[1]*w0.y, xf[2]*w0.z, xf[3]*w0.w,
                       xf[4]*w1.x, xf[5]*w1.y, xf[6]*w1.z, xf[7]*w1.w};
        bf16x8 a = __builtin_bit_cast(bf16x8, pack8(fs));
        #pragma unroll
        for (int nj = 0; nj < 4; nj++) {
            bf16x8 bb = *(const bf16x8*)&BT[xts(nj * 16 + lr, ks * 32 + lq * 8)];
            accs[nj] = __builtin_amdgcn_mfma_f32_16x16x32_bf16(a, bb, accs[nj], 0, 0, 0);
        }
    }
    // ---- S_c store: LDS-transpose through dead BT, then coalesced uint4 ----
    __syncthreads();                                 // all waves done reading BT/XT
    #pragma unroll
    for (int nj = 0; nj < 4; nj++)
        #pragma unroll
        for (int r = 0; r < 4; r++) {
            int p = w * 16 + lq * 4 + r, n = nj * 16 + lr;
            BT[p * 72 + n] = f2b(accs[nj][r]);       // [p][n] stride 72 (64*72 <= 8768)
        }
    __syncthreads();
    #pragma unroll
    for (int k2 = 0; k2 < 2; k2++) {
        int c2 = k2 * 256 + tid;
        int p = c2 >> 3, n0 = (c2 & 7) * 8;
        *(uint4*)(scb + (size_t)blk * 4096 + p * 64 + n0) = *(const uint4*)&BT[p * 72 + n0];
    }
    if (tid < 128) wout[dbh * 2048 + s0 + tid] = __expf((float)cumd[tid]);
    if (tid == 0)  decay[blk] = __expf((float)cumd[127]);
}

// ---------- h-state scan (barrier-free): rewrites scb slots in place with h_in per chunk ----------
// elementwise recurrence h = decay*h + S_c over 16 chunks; 4 blocks per dbh
// (1024 blocks) for 4x TLP; each thread owns 4 slots (8B coalesced).
__global__ __launch_bounds__(256) void k_hscan(const float* __restrict__ decay, u16* __restrict__ scb) {
    int bid = blockIdx.x;                 // 1024 = 256 dbh x 4 slices
    int dbh = bid >> 2, ps = bid & 3;
    int tid = threadIdx.x;
    u16* base = scb + (size_t)dbh * 16 * 4096 + ps * 1024 + tid * 4;
    float h0 = 0.f, h1 = 0.f, h2 = 0.f, h3 = 0.f;
    for (int c = 0; c < NCH; c++) {
        u16* sg = base + (size_t)c * 4096;
        uint2 q = *(const uint2*)sg;
        float s0 = b2f(q.x & 0xffffu), s1 = b2f(q.x >> 16);
        float s2 = b2f(q.y & 0xffffu), s3 = b2f(q.y >> 16);
        uint2 o;
        o.x = (u32)f2b(h0) | ((u32)f2b(h1) << 16);
        o.y = (u32)f2b(h2) | ((u32)f2b(h3) << 16);
        *(uint2*)sg = o;                  // h entering chunk c
        float dk = decay[dbh * 16 + c];
        h0 = dk * h0 + s0; h1 = dk * h1 + s1;
        h2 = dk * h2 + s2; h3 = dk * h3 + s3;
    }
}

// ---------- inter-chunk contribution (parallel): y += (wout.*C) * h_in^T ----------
// R5: y-RMW now staged as f32 through LDS (identical arithmetic: f32 add then
// one bf16 round) and issued as coalesced uint4 load+store (was 64 scalar 2B
// VMEM ops per thread).
__global__ __launch_bounds__(256) void k_inter(const u16* __restrict__ BCb, const float* __restrict__ wout,
                                               const u16* __restrict__ hin, u16* __restrict__ y0,
                                               u16* __restrict__ y1) {
    __shared__ __align__(16) u16 smem[18432];        // Csc [0,9216) stride 72; hs [9216,13824); f32 [128][68] y-stage overlays
    u16* Csc = smem;
    u16* hs  = smem + 9216;
    float* fsm = (float*)smem;
    const int blk = blockIdx.x;
    const int c = blk & 15, dbh = blk >> 4;
    const int h = dbh & 31, b = (dbh >> 5) & 3, dir = dbh >> 7;
    const int tid = threadIdx.x, w = tid >> 6, lane = tid & 63, lr = lane & 15, lq = lane >> 4;
    u16* yo = dir ? y1 : y0;

    {   // stage h_in (p-major 64x64 -> padded rows)
        int g = tid * 16, p = g >> 6, n = g & 63;
        const u16* hg = hin + (size_t)blk * 4096 + g;
        *(uint4*)&hs[p * 72 + n]     = *(const uint4*)hg;
        *(uint4*)&hs[p * 72 + n + 8] = *(const uint4*)(hg + 8);
    }
    const int sl0 = tid >> 3, ng = (tid & 7) * 8;
    #pragma unroll
    for (int it = 0; it < 4; it++) {
        int sl = sl0 + it * 32;
        int s = c * QC + sl;
        int t = dir ? (L_ - 1 - s) : s;
        const u16* bcr = BCb + ((size_t)b * L_ + t) * 128 + 64 + ng;
        float sc = wout[dbh * 2048 + s];
        uint4 cv = *(const uint4*)bcr;
        float cf[8]; unpack8(cv, cf);
        float f[8] = {cf[0]*sc, cf[1]*sc, cf[2]*sc, cf[3]*sc, cf[4]*sc, cf[5]*sc, cf[6]*sc, cf[7]*sc};
        *(uint4*)&Csc[sl * 72 + ng] = pack8(f);
    }
    __syncthreads();
    f32x4 acc[2][4];
    #pragma unroll
    for (int ti = 0; ti < 2; ti++)
        #pragma unroll
        for (int pj = 0; pj < 4; pj++) acc[ti][pj] = (f32x4){0.f, 0.f, 0.f, 0.f};
    #pragma unroll
    for (int ks = 0; ks < 2; ks++) {
        bf16x8 a0 = *(const bf16x8*)&Csc[(w * 32 + lr) * 72 + ks * 32 + lq * 8];
        bf16x8 a1 = *(const bf16x8*)&Csc[(w * 32 + 16 + lr) * 72 + ks * 32 + lq * 8];
        #pragma unroll
        for (int pj = 0; pj < 4; pj++) {
            bf16x8 bb = *(const bf16x8*)&hs[(pj * 16 + lr) * 72 + ks * 32 + lq * 8];
            acc[0][pj] = __builtin_amdgcn_mfma_f32_16x16x32_bf16(a0, bb, acc[0][pj], 0, 0, 0);
            acc[1][pj] = __builtin_amdgcn_mfma_f32_16x16x32_bf16(a1, bb, acc[1][pj], 0, 0, 0);
        }
    }
    // ---- f32 LDS transpose (smem dead after barrier), then coalesced uint4 RMW ----
    __syncthreads();                                 // Csc/hs reads complete
    #pragma unroll
    for (int ti = 0; ti < 2; ti++)
        #pragma unroll
        for (int pj = 0; pj < 4; pj++)
            #pragma unroll
            for (int r = 0; r < 4; r++) {
                int t_l = w * 32 + ti * 16 + lq * 4 + r;
                fsm[t_l * 68 + pj * 16 + lr] = acc[ti][pj][r];   // [t][p] stride 68 f32
            }
    __syncthreads();
    #pragma unroll
    for (int k2 = 0; k2 < 4; k2++) {
        int c2 = k2 * 256 + tid;
        int t_l = c2 >> 3, p0 = (c2 & 7) * 8;
        int s = c * QC + t_l;
        int t = dir ? (L_ - 1 - s) : s;
        u16* yp = yo + ((size_t)b * L_ + t) * DIN + h * 64 + p0;
        uint4 ov = *(const uint4*)yp;
        float of[8]; unpack8(ov, of);
        const float4 v0 = *(const float4*)&fsm[t_l * 68 + p0];
        const float4 v1 = *(const float4*)&fsm[t_l * 68 + p0 + 4];
        float nf[8] = {of[0] + v0.x, of[1] + v0.y, of[2] + v0.z, of[3] + v0.w,
                       of[4] + v1.x, of[5] + v1.y, of[6] + v1.z, of[7] + v1.w};
        *(uint4*)yp = pack8(nf);                      // RMW own rows only — no races
    }
}

// ---------- gate + RMSNorm -> bf16 (shift folded into the y reads) ----------
__global__ __launch_bounds__(256) void k_gate(const u16* __restrict__ xs, const u16* __restrict__ zx,
                                              const u16* __restrict__ y0, const u16* __restrict__ y1,
                                              const float* __restrict__ Dd,
                                              const float* __restrict__ nw, u16* __restrict__ yn) {
    int row = blockIdx.x, tid = threadIdx.x;
    int t = row & (L_ - 1);
    __shared__ float red[4];
    size_t base = (size_t)row * DIN;
    uint4 xv = ((const uint4*)(xs + base))[tid];
    uint4 zv = ((const uint4*)(zx + (size_t)row * NPAD))[tid];
    uint4 zero4 = {0u, 0u, 0u, 0u};
    uint4 a0 = (t > 0)      ? ((const uint4*)(y0 + base - DIN))[tid] : zero4;   // y_fwd[t-1]
    uint4 a1 = (t < L_ - 1) ? ((const uint4*)(y1 + base + DIN))[tid] : zero4;   // y_bwd[t+1]
    float sD = Dd[(size_t)row * 32 + (tid >> 3)];
    float xf[8], zf[8], f0[8], f1[8];
    unpack8(xv, xf); unpack8(zv, zf); unpack8(a0, f0); unpack8(a1, f1);
    int d0 = tid * 8;
    float g[8]; float ss = 0.f;
    #pragma unroll
    for (int i = 0; i < 8; i++) {
        float yv = f0[i] + f1[i] + xf[i] * sD;
        float z = zf[i];
        float gg = yv * (z / (1.f + __expf(-z)));
        g[i] = gg; ss += gg * gg;
    }
    for (int o = 32; o; o >>= 1) ss += __shfl_down(ss, o);
    if ((tid & 63) == 0) red[tid >> 6] = ss;
    __syncthreads();
    float tot = red[0] + red[1] + red[2] + red[3];
    float r = rsqrtf(tot * (1.f / DIN) + EPS);
    float o8[8];
    #pragma unroll
    for (int i = 0; i < 8; i++) o8[i] = g[i] * r * nw[d0 + i];
    ((uint4*)(yn + base))[tid] = pack8(o8);
}

// ---------- workspace layout (bytes) ----------
#define OFF_U     ((size_t)0)                       // BL*DM bf16 (dead after GEMM1)
#define OFF_WIN   ((size_t)16777216)                // NPAD*DM bf16
#define OFF_WOUT  ((size_t)25690112)                // DM*DIN bf16
#define OFF_ZX    ((size_t)29884416)                // BL*NPAD bf16
#define OFF_XS    ((size_t)101187584)               // BL*DIN bf16
#define OFF_BC    ((size_t)134742016)               // BL*128 bf16 = 2 MB
#define OFF_DTA   ((size_t)138936320)               // (unused)
#define OFF_Y0    ((size_t)143130624)               // BL*DIN bf16
#define OFF_Y1    ((size_t)176685056)               // BL*DIN bf16
#define OFF_YN    ((size_t)210239488)               // BL*DIN bf16 (gate out); scb/h_in aliases earlier
// aliases inside dead OFF_U region:
#define OFF_WO2   OFF_U                             // 256*2048 f32 = 2 MB
#define OFF_DEC   (OFF_U + 2097152)                 // 4096 f32
#define OFF_FCB   (OFF_U + 2113536)                 // NH*DIN bf16 = 128 KB
#define OFF_DD    (OFF_U + 2244608)                 // BL*32 f32 = 1 MB
#define OFF_SCB   OFF_YN                            // 4096*4096 bf16 = 33.5 MB (S_c -> h_in in place; dead before k_gate writes yn)
// total 243,793,920 bytes

extern "C" void kernel_launch(void* const* d_in, const int* in_sizes, int n_in,
                              void* d_out, int out_size, void* d_ws, size_t ws_size,
                              hipStream_t stream) {
    const float* x       = (const float*)d_in[0];
    const float* ln_g    = (const float*)d_in[1];
    const float* ln_b    = (const float*)d_in[2];
    const float* W_in    = (const float*)d_in[3];
    const float* conv_w  = (const float*)d_in[4];
    const float* conv_b  = (const float*)d_in[5];
    const float* dt_bias = (const float*)d_in[6];
    const float* A_log   = (const float*)d_in[7];
    const float* fc_D_w  = (const float*)d_in[8];
    const float* Dv      = (const float*)d_in[9];
    const float* norm_w  = (const float*)d_in[10];
    const float* W_out   = (const float*)d_in[11];

    char* ws = (char*)d_ws;
    u16*   u_bf  = (u16*)(ws + OFF_U);
    u16*   winb  = (u16*)(ws + OFF_WIN);
    u16*   woutb = (u16*)(ws + OFF_WOUT);
    u16*   zx    = (u16*)(ws + OFF_ZX);
    u16*   xs    = (u16*)(ws + OFF_XS);
    u16*   BCb   = (u16*)(ws + OFF_BC);
    u16*   y0b   = (u16*)(ws + OFF_Y0);
    u16*   y1b   = (u16*)(ws + OFF_Y1);
    u16*   ynb   = (u16*)(ws + OFF_YN);
    float* wo2   = (float*)(ws + OFF_WO2);
    float* dec   = (float*)(ws + OFF_DEC);
    u16*   fcb   = (u16*)(ws + OFF_FCB);
    float* Dd    = (float*)(ws + OFF_DD);
    u16*   scb   = (u16*)(ws + OFF_SCB);

    k_cvt_win <<<(NPAD * DM) / 256, 256, 0, stream>>>(W_in, winb);
    k_cvt_wout<<<(DM * DIN) / 256, 256, 0, stream>>>(W_out, woutb);
    k_ln      <<<BL, 256, 0, stream>>>(x, ln_g, ln_b, u_bf);
    k_gemm_bt <<<dim3(NPAD / 128, BL / 128), 256, 0, stream>>>(u_bf, winb, BL, NPAD, DM, 1, zx, NPAD, nullptr, nullptr);
    k_cvt_fcd <<<(NH * DIN) / 256, 256, 0, stream>>>(fc_D_w, fcb);
    k_conv    <<<dim3(CONV_DIM / 64, L_ / 256, B_), 256, 0, stream>>>(zx, conv_w, conv_b, xs, BCb);
    k_dproj   <<<BL / 32, 256, 0, stream>>>(xs, fcb, Dv, Dd);
    k_chunk   <<<4096, 256, 0, stream>>>(xs, BCb, zx, dt_bias, A_log, y0b, y1b, wo2, dec, scb);
    k_hscan   <<<1024, 256, 0, stream>>>(dec, scb);
    k_inter   <<<4096, 256, 0, stream>>>(BCb, wo2, scb, y0b, y1b);
    k_gate    <<<BL, 256, 0, stream>>>(xs, zx, y0b, y1b, Dd, norm_w, ynb);
    k_gemm_bt <<<dim3(DM / 128, BL / 128), 256, 0, stream>>>(ynb, woutb, BL, DM, DIN, 0, nullptr, DM, (float*)d_out, x);
}

// Round 7
// 519.350 us; speedup vs baseline: 1.0512x; 1.0025x over previous
//
#include <hip/hip_runtime.h>
#include <stdint.h>

// ---- problem constants ----
#define B_   4
#define L_   2048
#define DM   1024
#define DIN  2048
#define NH   32
#define HD   64
#define DSTATE 64
#define DCONV  7
#define CONV_DIM 2176            // DIN + 2*DSTATE
#define DPROJ 4288               // 2*DIN + 2*DSTATE + 2*NH
#define NPAD 4352                // DPROJ padded to 128
#define BL   8192                // B_*L_
#define EPS  1e-5f
#define QC   128                 // scan chunk length
#define NCH  16                  // chunks per sequence

typedef unsigned short u16;
typedef unsigned int   u32;
typedef __bf16 bf16x8 __attribute__((ext_vector_type(8)));
typedef float  f32x4  __attribute__((ext_vector_type(4)));

__device__ __forceinline__ float b2f(u32 b) { return __uint_as_float(b << 16); }
__device__ __forceinline__ u16 f2b(float f) {
    u32 u = __float_as_uint(f);
    u32 r = (u + 0x7fffu + ((u >> 16) & 1u)) >> 16;
    return (u16)r;
}
__device__ __forceinline__ void unpack8(uint4 v, float* f) {
    f[0] = b2f(v.x & 0xffffu); f[1] = b2f(v.x >> 16);
    f[2] = b2f(v.y & 0xffffu); f[3] = b2f(v.y >> 16);
    f[4] = b2f(v.z & 0xffffu); f[5] = b2f(v.z >> 16);
    f[6] = b2f(v.w & 0xffffu); f[7] = b2f(v.w >> 16);
}
__device__ __forceinline__ uint4 pack8(const float* f) {
    uint4 v;
    v.x = (u32)f2b(f[0]) | ((u32)f2b(f[1]) << 16);
    v.y = (u32)f2b(f[2]) | ((u32)f2b(f[3]) << 16);
    v.z = (u32)f2b(f[4]) | ((u32)f2b(f[5]) << 16);
    v.w = (u32)f2b(f[6]) | ((u32)f2b(f[7]) << 16);
    return v;
}
// skewed LDS index for transposed tiles: row-stride 136 u16 + 8-u16 skew per 8 rows.
__device__ __forceinline__ int xts(int p, int s) { return p * 136 + ((p >> 3) << 3) + s; }
// async global->LDS, 16B per lane; lds base must be wave-uniform (HW adds lane*16)
__device__ __forceinline__ void gload_lds16(const u16* g, u16* l) {
    __builtin_amdgcn_global_load_lds((const __attribute__((address_space(1))) void*)g,
                                     (__attribute__((address_space(3))) void*)l, 16, 0, 0);
}

// ---------- weight conversion (vectorized x4: float4 load, uint2 store) ----------
__global__ __launch_bounds__(256) void k_cvt_win(const float* __restrict__ W, u16* __restrict__ Wb) {
    int idx4 = (blockIdx.x * 256 + threadIdx.x) * 4;   // over NPAD*DM, 4 cols/thread
    int n = idx4 >> 10;                                 // DM = 1024, col%4==0 so same n
    int col = idx4 & 1023;
    uint2 p = {0u, 0u};
    if (n < DPROJ) {
        float4 v = *(const float4*)(W + (size_t)n * DM + col);
        p.x = (u32)f2b(v.x) | ((u32)f2b(v.y) << 16);
        p.y = (u32)f2b(v.z) | ((u32)f2b(v.w) << 16);
    }
    *(uint2*)(Wb + idx4) = p;
}
__global__ __launch_bounds__(256) void k_cvt_wout(const float* __restrict__ W, u16* __restrict__ Wb) {
    int idx4 = (blockIdx.x * 256 + threadIdx.x) * 4;   // over DM*DIN
    float4 v = *(const float4*)(W + idx4);
    uint2 p;
    p.x = (u32)f2b(v.x) | ((u32)f2b(v.y) << 16);
    p.y = (u32)f2b(v.z) | ((u32)f2b(v.w) << 16);
    *(uint2*)(Wb + idx4) = p;
}
__global__ __launch_bounds__(256) void k_cvt_fcd(const float* __restrict__ W, u16* __restrict__ Wb) {
    int idx4 = (blockIdx.x * 256 + threadIdx.x) * 4;   // over NH*DIN
    float4 v = *(const float4*)(W + idx4);
    uint2 p;
    p.x = (u32)f2b(v.x) | ((u32)f2b(v.y) << 16);
    p.y = (u32)f2b(v.z) | ((u32)f2b(v.w) << 16);
    *(uint2*)(Wb + idx4) = p;
}

// ---------- layernorm -> bf16 ----------
__global__ __launch_bounds__(256) void k_ln(const float* __restrict__ x, const float* __restrict__ g,
                                            const float* __restrict__ be, u16* __restrict__ u) {
    int row = blockIdx.x, tid = threadIdx.x;
    const float4* xr = (const float4*)(x + (size_t)row * DM);
    float4 v = xr[tid];
    float s1 = v.x + v.y + v.z + v.w;
    float s2 = v.x * v.x + v.y * v.y + v.z * v.z + v.w * v.w;
    for (int o = 32; o; o >>= 1) { s1 += __shfl_down(s1, o); s2 += __shfl_down(s2, o); }
    __shared__ float ls1[4], ls2[4];
    int w = tid >> 6;
    if ((tid & 63) == 0) { ls1[w] = s1; ls2[w] = s2; }
    __syncthreads();
    float t1 = ls1[0] + ls1[1] + ls1[2] + ls1[3];
    float t2 = ls2[0] + ls2[1] + ls2[2] + ls2[3];
    float mu = t1 * (1.f / DM);
    float var = t2 * (1.f / DM) - mu * mu;
    float rs = rsqrtf(var + EPS);
    float4 gv = ((const float4*)g)[tid];
    float4 bv = ((const float4*)be)[tid];
    float o0 = (v.x - mu) * rs * gv.x + bv.x;
    float o1 = (v.y - mu) * rs * gv.y + bv.y;
    float o2 = (v.z - mu) * rs * gv.z + bv.z;
    float o3 = (v.w - mu) * rs * gv.w + bv.w;
    uint2 p;
    p.x = (u32)f2b(o0) | ((u32)f2b(o1) << 16);
    p.y = (u32)f2b(o2) | ((u32)f2b(o3) << 16);
    ((uint2*)(u + (size_t)row * DM))[tid] = p;
}

// ---------- bf16 MFMA GEMM, C[m,n] = sum_k A[m,k]*B[n,k]  (B^T layout) ----------
// 128x128 tile, 2-barrier K-loop, global_load_lds width=16 staging (proven m97
// structure). 256^2 deep-pipeline variants tried in rounds 1-4 all regressed
// (103-120 us, MfmaUtil <30%) -- do not revisit without new evidence.
// NOTE: identical code measured 95.4 us (r0/r6) vs ~112 us (r5) on different
// acquisitions -- cross-acquisition noise is ~+/-10%.
__global__ __launch_bounds__(256) void k_gemm_bt(const u16* __restrict__ A, const u16* __restrict__ Bw,
                                                 int M, int N, int K, int out_bf16,
                                                 u16* __restrict__ obf, int ldo,
                                                 float* __restrict__ ofp, const float* __restrict__ res) {
    __shared__ __align__(16) u16 As[128 * 64];
    __shared__ __align__(16) u16 Bs[128 * 64];
    int tid = threadIdx.x;
    int m0 = blockIdx.y * 128, n0 = blockIdx.x * 128;
    int w = tid >> 6, lane = tid & 63;
    int wm = (w >> 1) * 64, wn = (w & 1) * 64;
    int lr = lane & 15, lq = lane >> 4;

    f32x4 acc[4][4];
    #pragma unroll
    for (int i = 0; i < 4; i++)
        #pragma unroll
        for (int j = 0; j < 4; j++) acc[i][j] = (f32x4){0.f, 0.f, 0.f, 0.f};

    for (int kt = 0; kt < K; kt += 64) {
        #pragma unroll
        for (int it = 0; it < 4; it++) {
            int s_idx = it * 256 + tid;
            int row = s_idx >> 3;
            int kcg = (s_idx & 7) ^ (row & 7);            // swizzled source chunk
            u16* lbase_a = &As[(it * 256 + w * 64) * 8];  // wave-uniform
            u16* lbase_b = &Bs[(it * 256 + w * 64) * 8];
            gload_lds16(A + (size_t)(m0 + row) * K + kt + kcg * 8, lbase_a);
            gload_lds16(Bw + (size_t)(n0 + row) * K + kt + kcg * 8, lbase_b);
        }
        __syncthreads();
        #pragma unroll
        for (int kk = 0; kk < 2; kk++) {
            bf16x8 af[4], bfr[4];
            #pragma unroll
            for (int i = 0; i < 4; i++) {
                int row = wm + 16 * i + lr;
                af[i] = *(const bf16x8*)&As[row * 64 + (((kk * 4 + lq)) ^ (row & 7)) * 8];
            }
            #pragma unroll
            for (int j = 0; j < 4; j++) {
                int row = wn + 16 * j + lr;
                bfr[j] = *(const bf16x8*)&Bs[row * 64 + (((kk * 4 + lq)) ^ (row & 7)) * 8];
            }
            #pragma unroll
            for (int i = 0; i < 4; i++)
                #pragma unroll
                for (int j = 0; j < 4; j++)
                    acc[i][j] = __builtin_amdgcn_mfma_f32_16x16x32_bf16(af[i], bfr[j], acc[i][j], 0, 0, 0);
        }
        __syncthreads();
    }
    #pragma unroll
    for (int i = 0; i < 4; i++) {
        #pragma unroll
        for (int j = 0; j < 4; j++) {
            #pragma unroll
            for (int rr = 0; rr < 4; rr++) {
                int m = m0 + wm + 16 * i + lq * 4 + rr;
                int n = n0 + wn + 16 * j + lr;
                float v = acc[i][j][rr];
                if (out_bf16) obf[(size_t)m * ldo + n] = f2b(v);
                else          ofp[(size_t)m * ldo + n] = v + res[(size_t)m * ldo + n];
            }
        }
    }
}

// ---------- Dd init: Dd[m][h] = Dv[h] (seed for atomic split-K dproj) ----------
__global__ __launch_bounds__(256) void k_dzero(const float* __restrict__ Dv, float* __restrict__ Dd) {
    int idx = blockIdx.x * 256 + threadIdx.x;           // over BL*32
    Dd[idx] = Dv[idx & 31];
}

// ---------- D-projection GEMM, split-K x8: Dd[m][h] += partial dot(xs[m,:], fc_D_w[h,:]) ----------
// r7: was 256 blocks = 1 block/CU with a serial load->barrier->use K-loop
// (latency-bound, ~15 us for 1 GFLOP). Now grid (256 m-blocks x 8 k-slices),
// 4 iters/block, f32 atomicAdd (8 low-contention adds per output).
__global__ __launch_bounds__(256) void k_dproj(const u16* __restrict__ xs, const u16* __restrict__ fcb,
                                               float* __restrict__ Dd) {
    __shared__ __align__(16) u16 As[32 * 72];
    __shared__ __align__(16) u16 Bs[32 * 72];
    int tid = threadIdx.x;
    int m0 = blockIdx.x * 32;
    int k0 = blockIdx.y * 256;                          // 8 K-slices of 256
    int w = tid >> 6, lane = tid & 63, lr = lane & 15, lq = lane >> 4;
    int mt = (w & 1) * 16, nt = (w >> 1) * 16;
    int r = tid >> 3, kc = tid & 7;
    f32x4 acc = (f32x4){0.f, 0.f, 0.f, 0.f};
    for (int kt = k0; kt < k0 + 256; kt += 64) {
        *(uint4*)&As[r * 72 + kc * 8] = *(const uint4*)(xs + (size_t)(m0 + r) * DIN + kt + kc * 8);
        *(uint4*)&Bs[r * 72 + kc * 8] = *(const uint4*)(fcb + (size_t)r * DIN + kt + kc * 8);
        __syncthreads();
        #pragma unroll
        for (int ks = 0; ks < 2; ks++) {
            bf16x8 a = *(const bf16x8*)&As[(mt + lr) * 72 + ks * 32 + lq * 8];
            bf16x8 b = *(const bf16x8*)&Bs[(nt + lr) * 72 + ks * 32 + lq * 8];
            acc = __builtin_amdgcn_mfma_f32_16x16x32_bf16(a, b, acc, 0, 0, 0);
        }
        __syncthreads();
    }
    #pragma unroll
    for (int rr = 0; rr < 4; rr++) {
        int m = m0 + mt + lq * 4 + rr;
        int n = nt + lr;
        atomicAdd(&Dd[(size_t)m * 32 + n], acc[rr]);
    }
}

// ---------- depthwise conv7 (same-pad) + bias + SiLU, split xs / BC(bf16) ----------
__global__ __launch_bounds__(256) void k_conv(const u16* __restrict__ zx, const float* __restrict__ cw,
                                              const float* __restrict__ cb, u16* __restrict__ xs,
                                              u16* __restrict__ BCb) {
    __shared__ u16 sh[262 * 64];
    int c0 = blockIdx.x * 64, t0 = blockIdx.y * 256, b = blockIdx.z;
    int tid = threadIdx.x;
    int c = tid & 63, tg = tid >> 6;
    for (int it = 0; it < 66; it++) {
        int r = it * 4 + tg;
        if (r < 262) {
            int t = t0 + r - 3;
            u16 v = 0;
            if (t >= 0 && t < L_) v = zx[(size_t)(b * L_ + t) * NPAD + DIN + c0 + c];
            sh[r * 64 + c] = v;
        }
    }
    float wgt[7];
    #pragma unroll
    for (int k = 0; k < 7; k++) wgt[k] = cw[(c0 + c) * 7 + k];
    float bias = cb[c0 + c];
    __syncthreads();
    int cg = c0 + c;
    for (int tt = 0; tt < 64; tt++) {
        int tl = tt * 4 + tg;
        float a = bias;
        #pragma unroll
        for (int k = 0; k < 7; k++) a += b2f(sh[(tl + k) * 64 + c]) * wgt[k];
        float v = a / (1.f + __expf(-a));   // silu
        size_t row = (size_t)b * L_ + (t0 + tl);
        if (cg < DIN) xs[row * DIN + cg] = f2b(v);
        else          BCb[row * 128 + (cg - DIN)] = f2b(v);   // B at [0,64), C at [64,128), bf16
    }
}

// ======================================================================
// Chunked SSD scan (intra-chunk + chunk-state + inline dt): block = (dir,b,h,chunk).
// R5: outputs staged through dead LDS, coalesced uint4 stores.
// R7: Y and S_c MFMA groups merged before a single barrier (tail barriers
// 4 -> 2; both read disjoint stable LDS), then both staged, then both stored.
// ======================================================================
__global__ __launch_bounds__(256) void k_chunk(const u16* __restrict__ xs, const u16* __restrict__ BCb,
                                               const u16* __restrict__ zx, const float* __restrict__ dt_bias,
                                               const float* __restrict__ A_log, u16* __restrict__ y0,
                                               u16* __restrict__ y1, float* __restrict__ wout,
                                               float* __restrict__ decay, u16* __restrict__ scb) {
    __shared__ __align__(16) u16 ab[18432];      // Cs [0,9216) stride 72, Bs [9216,18432); S overlays (skewed 136); y-stage overlays [t][72]
    __shared__ __align__(16) u16 XT[8768];       // X^T [p][s] skewed
    __shared__ __align__(16) u16 BT[8768];       // B^T [n][s] skewed; scb-stage overlays [p][72]
    __shared__ __align__(16) float dts_s[128];
    __shared__ __align__(16) float lda_s[128];
    __shared__ __align__(16) float wend[128];
    __shared__ __align__(16) double cumd[128];

    const int blk = blockIdx.x;
    const int c = blk & 15, dbh = blk >> 4;
    const int h = dbh & 31, b = (dbh >> 5) & 3, dir = dbh >> 7;
    const int tid = threadIdx.x, w = tid >> 6, lane = tid & 63, lr = lane & 15, lq = lane >> 4;
    const int s0 = c * QC;
    u16* yo = dir ? y1 : y0;

    if (tid < 128) {   // inline dt2 / log-dA
        int s = s0 + tid;
        int t = dir ? (L_ - 1 - s) : s;
        float draw = b2f(zx[(size_t)(b * L_ + t) * NPAD + (DIN + CONV_DIM) + dir * 32 + h]);
        float xb = draw + dt_bias[h];
        float dt2 = (xb > 20.f) ? xb : log1pf(__expf(xb));
        dts_s[tid] = dt2;
        lda_s[tid] = -__expf(A_log[h]) * dt2;
    }
    {   // stage Cs, Bs (bf16 row-major), BT, XT (transposed, skewed)
        int sl0 = tid >> 3, ng = (tid & 7) * 8;
        #pragma unroll
        for (int it = 0; it < 4; it++) {
            int sl = sl0 + it * 32;
            int s = s0 + sl;
            int t = dir ? (L_ - 1 - s) : s;
            size_t row = (size_t)b * L_ + t;
            const u16* bcr = BCb + row * 128;
            uint4 cv = *(const uint4*)(bcr + 64 + ng);
            *(uint4*)&ab[sl * 72 + ng] = cv;
            uint4 pb = *(const uint4*)(bcr + ng);
            *(uint4*)&ab[9216 + sl * 72 + ng] = pb;
            u16 bh[8] = {(u16)(pb.x & 0xffffu), (u16)(pb.x >> 16), (u16)(pb.y & 0xffffu), (u16)(pb.y >> 16),
                         (u16)(pb.z & 0xffffu), (u16)(pb.z >> 16), (u16)(pb.w & 0xffffu), (u16)(pb.w >> 16)};
            #pragma unroll
            for (int i = 0; i < 8; i++) BT[(ng + i) * 136 + ng + sl] = bh[i];   // skew = ng
            uint4 xv = *(const uint4*)(xs + row * DIN + h * 64 + ng);
            u16 xh[8] = {(u16)(xv.x & 0xffffu), (u16)(xv.x >> 16), (u16)(xv.y & 0xffffu), (u16)(xv.y >> 16),
                         (u16)(xv.z & 0xffffu), (u16)(xv.z >> 16), (u16)(xv.w & 0xffffu), (u16)(xv.w >> 16)};
            #pragma unroll
            for (int i = 0; i < 8; i++) XT[(ng + i) * 136 + ng + sl] = xh[i];   // skew = ng
        }
    }
    __syncthreads();
    if (w == 0) {   // double-precision inclusive prefix of log-dA (wave 0)
        double v0 = (double)lda_s[lane];
        double v1 = (double)lda_s[64 + lane];
        #pragma unroll
        for (int o = 1; o < 64; o <<= 1) {
            double t0 = __shfl_up(v0, o);
            double t1 = __shfl_up(v1, o);
            if (lane >= o) { v0 += t0; v1 += t1; }
        }
        double tot0 = __shfl(v0, 63);
        cumd[lane] = v0;
        cumd[64 + lane] = tot0 + v1;
    }
    // G = C * B^T  (wave w owns t-rows [w*32, w*32+32))
    bf16x8 af[2][2];
    #pragma unroll
    for (int ti = 0; ti < 2; ti++)
        #pragma unroll
        for (int ks = 0; ks < 2; ks++)
            af[ti][ks] = *(const bf16x8*)&ab[(w * 32 + ti * 16 + lr) * 72 + ks * 32 + lq * 8];
    f32x4 accg[2][8];
    #pragma unroll
    for (int ti = 0; ti < 2; ti++)
        #pragma unroll
        for (int si = 0; si < 8; si++) accg[ti][si] = (f32x4){0.f, 0.f, 0.f, 0.f};
    #pragma unroll
    for (int si = 0; si < 8; si++)
        #pragma unroll
        for (int ks = 0; ks < 2; ks++) {
            bf16x8 bf = *(const bf16x8*)&ab[9216 + (si * 16 + lr) * 72 + ks * 32 + lq * 8];
            accg[0][si] = __builtin_amdgcn_mfma_f32_16x16x32_bf16(af[0][ks], bf, accg[0][si], 0, 0, 0);
            accg[1][si] = __builtin_amdgcn_mfma_f32_16x16x32_bf16(af[1][ks], bf, accg[1][si], 0, 0, 0);
        }
    __syncthreads();   // all G frag reads done; cumd ready
    // wend[s] = exp(cum[127]-cum[s])*dt[s]  (for chunk-state); visible after next barrier
    if (tid < 128) wend[tid] = __expf((float)(cumd[127] - cumd[tid])) * dts_s[tid];
    // S = M .* G  -> overlay into ab (skewed stride 136)
    {
        double cumt_d[8];
        #pragma unroll
        for (int ti = 0; ti < 2; ti++)
            #pragma unroll
            for (int r = 0; r < 4; r++) cumt_d[ti * 4 + r] = cumd[w * 32 + ti * 16 + lq * 4 + r];
        double cums_d[8]; float dts_l[8];
        #pragma unroll
        for (int si = 0; si < 8; si++) { cums_d[si] = cumd[si * 16 + lr]; dts_l[si] = dts_s[si * 16 + lr]; }
        #pragma unroll
        for (int ti = 0; ti < 2; ti++)
            #pragma unroll
            for (int si = 0; si < 8; si++)
                #pragma unroll
                for (int r = 0; r < 4; r++) {
                    int t_l = w * 32 + ti * 16 + lq * 4 + r;
                    int s_l = si * 16 + lr;
                    float v = 0.f;
                    if (s_l <= t_l)
                        v = __expf((float)(cumt_d[ti * 4 + r] - cums_d[si])) * dts_l[si] * accg[ti][si][r];
                    ab[xts(t_l, s_l)] = f2b(v);
                }
    }
    __syncthreads();
    // Y_intra = S * X^T
    f32x4 acc[2][4];
    #pragma unroll
    for (int ti = 0; ti < 2; ti++)
        #pragma unroll
        for (int pj = 0; pj < 4; pj++) acc[ti][pj] = (f32x4){0.f, 0.f, 0.f, 0.f};
    #pragma unroll
    for (int ks = 0; ks < 4; ks++) {
        bf16x8 a0 = *(const bf16x8*)&ab[xts(w * 32 + lr, ks * 32 + lq * 8)];
        bf16x8 a1 = *(const bf16x8*)&ab[xts(w * 32 + 16 + lr, ks * 32 + lq * 8)];
        #pragma unroll
        for (int pj = 0; pj < 4; pj++) {
            bf16x8 bf = *(const bf16x8*)&XT[xts(pj * 16 + lr, ks * 32 + lq * 8)];
            acc[0][pj] = __builtin_amdgcn_mfma_f32_16x16x32_bf16(a0, bf, acc[0][pj], 0, 0, 0);
            acc[1][pj] = __builtin_amdgcn_mfma_f32_16x16x32_bf16(a1, bf, acc[1][pj], 0, 0, 0);
        }
    }
    // chunk state S_c[p][n] = sum_s wend[s]*x[s][p]*B[s][n]  (merged: reads stable XT/BT/wend)
    f32x4 accs[4];
    #pragma unroll
    for (int nj = 0; nj < 4; nj++) accs[nj] = (f32x4){0.f, 0.f, 0.f, 0.f};
    #pragma unroll
    for (int ks = 0; ks < 4; ks++) {
        uint4 xv = *(const uint4*)&XT[xts(w * 16 + lr, ks * 32 + lq * 8)];
        float xf[8]; unpack8(xv, xf);
        float4 w0 = *(const float4*)&wend[ks * 32 + lq * 8];
        float4 w1 = *(const float4*)&wend[ks * 32 + lq * 8 + 4];
        float fs[8] = {xf[0]*w0.x, xf[1]*w0.y, xf[2]*w0.z, xf[3]*w0.w,
                       xf[4]*w1.x, xf[5]*w1.y, xf[6]*w1.z, xf[7]*w1.w};
        bf16x8 a = __builtin_bit_cast(bf16x8, pack8(fs));
        #pragma unroll
        for (int nj = 0; nj < 4; nj++) {
            bf16x8 bb = *(const bf16x8*)&BT[xts(nj * 16 + lr, ks * 32 + lq * 8)];
            accs[nj] = __builtin_amdgcn_mfma_f32_16x16x32_bf16(a, bb, accs[nj], 0, 0, 0);
        }
    }
    // ---- single barrier: all LDS reads (S/XT/BT) complete; stage both outputs ----
    __syncthreads();
    #pragma unroll
    for (int ti = 0; ti < 2; ti++)
        #pragma unroll
        for (int pj = 0; pj < 4; pj++)
            #pragma unroll
            for (int r = 0; r < 4; r++) {
                int t_l = w * 32 + ti * 16 + lq * 4 + r;
                ab[t_l * 72 + pj * 16 + lr] = f2b(acc[ti][pj][r]);   // Y: [t][p] stride 72
            }
    #pragma unroll
    for (int nj = 0; nj < 4; nj++)
        #pragma unroll
        for (int r = 0; r < 4; r++) {
            int p = w * 16 + lq * 4 + r, n = nj * 16 + lr;
            BT[p * 72 + n] = f2b(accs[nj][r]);                       // S_c: [p][n] stride 72
        }
    __syncthreads();
    // ---- coalesced stores ----
    #pragma unroll
    for (int k2 = 0; k2 < 4; k2++) {
        int c2 = k2 * 256 + tid;
        int t_l = c2 >> 3, p0 = (c2 & 7) * 8;
        int s = s0 + t_l;
        int t = dir ? (L_ - 1 - s) : s;
        *(uint4*)(yo + ((size_t)b * L_ + t) * DIN + h * 64 + p0) = *(const uint4*)&ab[t_l * 72 + p0];
    }
    #pragma unroll
    for (int k2 = 0; k2 < 2; k2++) {
        int c2 = k2 * 256 + tid;
        int p = c2 >> 3, n0 = (c2 & 7) * 8;
        *(uint4*)(scb + (size_t)blk * 4096 + p * 64 + n0) = *(const uint4*)&BT[p * 72 + n0];
    }
    if (tid < 128) wout[dbh * 2048 + s0 + tid] = __expf((float)cumd[tid]);
    if (tid == 0)  decay[blk] = __expf((float)cumd[127]);
}

// ---------- h-state scan (barrier-free): rewrites scb slots in place with h_in per chunk ----------
// elementwise recurrence h = decay*h + S_c over 16 chunks; 4 blocks per dbh
// (1024 blocks) for 4x TLP; each thread owns 4 slots (8B coalesced).
__global__ __launch_bounds__(256) void k_hscan(const float* __restrict__ decay, u16* __restrict__ scb) {
    int bid = blockIdx.x;                 // 1024 = 256 dbh x 4 slices
    int dbh = bid >> 2, ps = bid & 3;
    int tid = threadIdx.x;
    u16* base = scb + (size_t)dbh * 16 * 4096 + ps * 1024 + tid * 4;
    float h0 = 0.f, h1 = 0.f, h2 = 0.f, h3 = 0.f;
    for (int c = 0; c < NCH; c++) {
        u16* sg = base + (size_t)c * 4096;
        uint2 q = *(const uint2*)sg;
        float s0 = b2f(q.x & 0xffffu), s1 = b2f(q.x >> 16);
        float s2 = b2f(q.y & 0xffffu), s3 = b2f(q.y >> 16);
        uint2 o;
        o.x = (u32)f2b(h0) | ((u32)f2b(h1) << 16);
        o.y = (u32)f2b(h2) | ((u32)f2b(h3) << 16);
        *(uint2*)sg = o;                  // h entering chunk c
        float dk = decay[dbh * 16 + c];
        h0 = dk * h0 + s0; h1 = dk * h1 + s1;
        h2 = dk * h2 + s2; h3 = dk * h3 + s3;
    }
}

// ---------- inter-chunk contribution (parallel): y += (wout.*C) * h_in^T ----------
// R5: y-RMW staged as f32 through LDS (identical arithmetic: f32 add then one
// bf16 round), coalesced uint4 load+store.
__global__ __launch_bounds__(256) void k_inter(const u16* __restrict__ BCb, const float* __restrict__ wout,
                                               const u16* __restrict__ hin, u16* __restrict__ y0,
                                               u16* __restrict__ y1) {
    __shared__ __align__(16) u16 smem[18432];        // Csc [0,9216) stride 72; hs [9216,13824); f32 [128][68] y-stage overlays
    u16* Csc = smem;
    u16* hs  = smem + 9216;
    float* fsm = (float*)smem;
    const int blk = blockIdx.x;
    const int c = blk & 15, dbh = blk >> 4;
    const int h = dbh & 31, b = (dbh >> 5) & 3, dir = dbh >> 7;
    const int tid = threadIdx.x, w = tid >> 6, lane = tid & 63, lr = lane & 15, lq = lane >> 4;
    u16* yo = dir ? y1 : y0;

    {   // stage h_in (p-major 64x64 -> padded rows)
        int g = tid * 16, p = g >> 6, n = g & 63;
        const u16* hg = hin + (size_t)blk * 4096 + g;
        *(uint4*)&hs[p * 72 + n]     = *(const uint4*)hg;
        *(uint4*)&hs[p * 72 + n + 8] = *(const uint4*)(hg + 8);
    }
    const int sl0 = tid >> 3, ng = (tid & 7) * 8;
    #pragma unroll
    for (int it = 0; it < 4; it++) {
        int sl = sl0 + it * 32;
        int s = c * QC + sl;
        int t = dir ? (L_ - 1 - s) : s;
        const u16* bcr = BCb + ((size_t)b * L_ + t) * 128 + 64 + ng;
        float sc = wout[dbh * 2048 + s];
        uint4 cv = *(const uint4*)bcr;
        float cf[8]; unpack8(cv, cf);
        float f[8] = {cf[0]*sc, cf[1]*sc, cf[2]*sc, cf[3]*sc, cf[4]*sc, cf[5]*sc, cf[6]*sc, cf[7]*sc};
        *(uint4*)&Csc[sl * 72 + ng] = pack8(f);
    }
    __syncthreads();
    f32x4 acc[2][4];
    #pragma unroll
    for (int ti = 0; ti < 2; ti++)
        #pragma unroll
        for (int pj = 0; pj < 4; pj++) acc[ti][pj] = (f32x4){0.f, 0.f, 0.f, 0.f};
    #pragma unroll
    for (int ks = 0; ks < 2; ks++) {
        bf16x8 a0 = *(const bf16x8*)&Csc[(w * 32 + lr) * 72 + ks * 32 + lq * 8];
        bf16x8 a1 = *(const bf16x8*)&Csc[(w * 32 + 16 + lr) * 72 + ks * 32 + lq * 8];
        #pragma unroll
        for (int pj = 0; pj < 4; pj++) {
            bf16x8 bb = *(const bf16x8*)&hs[(pj * 16 + lr) * 72 + ks * 32 + lq * 8];
            acc[0][pj] = __builtin_amdgcn_mfma_f32_16x16x32_bf16(a0, bb, acc[0][pj], 0, 0, 0);
            acc[1][pj] = __builtin_amdgcn_mfma_f32_16x16x32_bf16(a1, bb, acc[1][pj], 0, 0, 0);
        }
    }
    // ---- f32 LDS transpose (smem dead after barrier), then coalesced uint4 RMW ----
    __syncthreads();                                 // Csc/hs reads complete
    #pragma unroll
    for (int ti = 0; ti < 2; ti++)
        #pragma unroll
        for (int pj = 0; pj < 4; pj++)
            #pragma unroll
            for (int r = 0; r < 4; r++) {
                int t_l = w * 32 + ti * 16 + lq * 4 + r;
                fsm[t_l * 68 + pj * 16 + lr] = acc[ti][pj][r];   // [t][p] stride 68 f32
            }
    __syncthreads();
    #pragma unroll
    for (int k2 = 0; k2 < 4; k2++) {
        int c2 = k2 * 256 + tid;
        int t_l = c2 >> 3, p0 = (c2 & 7) * 8;
        int s = c * QC + t_l;
        int t = dir ? (L_ - 1 - s) : s;
        u16* yp = yo + ((size_t)b * L_ + t) * DIN + h * 64 + p0;
        uint4 ov = *(const uint4*)yp;
        float of[8]; unpack8(ov, of);
        const float4 v0 = *(const float4*)&fsm[t_l * 68 + p0];
        const float4 v1 = *(const float4*)&fsm[t_l * 68 + p0 + 4];
        float nf[8] = {of[0] + v0.x, of[1] + v0.y, of[2] + v0.z, of[3] + v0.w,
                       of[4] + v1.x, of[5] + v1.y, of[6] + v1.z, of[7] + v1.w};
        *(uint4*)yp = pack8(nf);                      // RMW own rows only — no races
    }
}

// ---------- gate + RMSNorm -> bf16 (shift folded into the y reads) ----------
__global__ __launch_bounds__(256) void k_gate(const u16* __restrict__ xs, const u16* __restrict__ zx,
                                              const u16* __restrict__ y0, const u16* __restrict__ y1,
                                              const float* __restrict__ Dd,
                                              const float* __restrict__ nw, u16* __restrict__ yn) {
    int row = blockIdx.x, tid = threadIdx.x;
    int t = row & (L_ - 1);
    __shared__ float red[4];
    size_t base = (size_t)row * DIN;
    uint4 xv = ((const uint4*)(xs + base))[tid];
    uint4 zv = ((const uint4*)(zx + (size_t)row * NPAD))[tid];
    uint4 zero4 = {0u, 0u, 0u, 0u};
    uint4 a0 = (t > 0)      ? ((const uint4*)(y0 + base - DIN))[tid] : zero4;   // y_fwd[t-1]
    uint4 a1 = (t < L_ - 1) ? ((const uint4*)(y1 + base + DIN))[tid] : zero4;   // y_bwd[t+1]
    float sD = Dd[(size_t)row * 32 + (tid >> 3)];
    float xf[8], zf[8], f0[8], f1[8];
    unpack8(xv, xf); unpack8(zv, zf); unpack8(a0, f0); unpack8(a1, f1);
    int d0 = tid * 8;
    float g[8]; float ss = 0.f;
    #pragma unroll
    for (int i = 0; i < 8; i++) {
        float yv = f0[i] + f1[i] + xf[i] * sD;
        float z = zf[i];
        float gg = yv * (z / (1.f + __expf(-z)));
        g[i] = gg; ss += gg * gg;
    }
    for (int o = 32; o; o >>= 1) ss += __shfl_down(ss, o);
    if ((tid & 63) == 0) red[tid >> 6] = ss;
    __syncthreads();
    float tot = red[0] + red[1] + red[2] + red[3];
    float r = rsqrtf(tot * (1.f / DIN) + EPS);
    float o8[8];
    #pragma unroll
    for (int i = 0; i < 8; i++) o8[i] = g[i] * r * nw[d0 + i];
    ((uint4*)(yn + base))[tid] = pack8(o8);
}

// ---------- workspace layout (bytes) ----------
#define OFF_U     ((size_t)0)                       // BL*DM bf16 (dead after GEMM1)
#define OFF_WIN   ((size_t)16777216)                // NPAD*DM bf16
#define OFF_WOUT  ((size_t)25690112)                // DM*DIN bf16
#define OFF_ZX    ((size_t)29884416)                // BL*NPAD bf16
#define OFF_XS    ((size_t)101187584)               // BL*DIN bf16
#define OFF_BC    ((size_t)134742016)               // BL*128 bf16 = 2 MB
#define OFF_DTA   ((size_t)138936320)               // (unused)
#define OFF_Y0    ((size_t)143130624)               // BL*DIN bf16
#define OFF_Y1    ((size_t)176685056)               // BL*DIN bf16
#define OFF_YN    ((size_t)210239488)               // BL*DIN bf16 (gate out); scb/h_in aliases earlier
// aliases inside dead OFF_U region:
#define OFF_WO2   OFF_U                             // 256*2048 f32 = 2 MB
#define OFF_DEC   (OFF_U + 2097152)                 // 4096 f32
#define OFF_FCB   (OFF_U + 2113536)                 // NH*DIN bf16 = 128 KB
#define OFF_DD    (OFF_U + 2244608)                 // BL*32 f32 = 1 MB
#define OFF_SCB   OFF_YN                            // 4096*4096 bf16 = 33.5 MB (S_c -> h_in in place; dead before k_gate writes yn)
// total 243,793,920 bytes

extern "C" void kernel_launch(void* const* d_in, const int* in_sizes, int n_in,
                              void* d_out, int out_size, void* d_ws, size_t ws_size,
                              hipStream_t stream) {
    const float* x       = (const float*)d_in[0];
    const float* ln_g    = (const float*)d_in[1];
    const float* ln_b    = (const float*)d_in[2];
    const float* W_in    = (const float*)d_in[3];
    const float* conv_w  = (const float*)d_in[4];
    const float* conv_b  = (const float*)d_in[5];
    const float* dt_bias = (const float*)d_in[6];
    const float* A_log   = (const float*)d_in[7];
    const float* fc_D_w  = (const float*)d_in[8];
    const float* Dv      = (const float*)d_in[9];
    const float* norm_w  = (const float*)d_in[10];
    const float* W_out   = (const float*)d_in[11];

    char* ws = (char*)d_ws;
    u16*   u_bf  = (u16*)(ws + OFF_U);
    u16*   winb  = (u16*)(ws + OFF_WIN);
    u16*   woutb = (u16*)(ws + OFF_WOUT);
    u16*   zx    = (u16*)(ws + OFF_ZX);
    u16*   xs    = (u16*)(ws + OFF_XS);
    u16*   BCb   = (u16*)(ws + OFF_BC);
    u16*   y0b   = (u16*)(ws + OFF_Y0);
    u16*   y1b   = (u16*)(ws + OFF_Y1);
    u16*   ynb   = (u16*)(ws + OFF_YN);
    float* wo2   = (float*)(ws + OFF_WO2);
    float* dec   = (float*)(ws + OFF_DEC);
    u16*   fcb   = (u16*)(ws + OFF_FCB);
    float* Dd    = (float*)(ws + OFF_DD);
    u16*   scb   = (u16*)(ws + OFF_SCB);

    k_cvt_win <<<(NPAD * DM) / 1024, 256, 0, stream>>>(W_in, winb);
    k_cvt_wout<<<(DM * DIN) / 1024, 256, 0, stream>>>(W_out, woutb);
    k_ln      <<<BL, 256, 0, stream>>>(x, ln_g, ln_b, u_bf);
    k_gemm_bt <<<dim3(NPAD / 128, BL / 128), 256, 0, stream>>>(u_bf, winb, BL, NPAD, DM, 1, zx, NPAD, nullptr, nullptr);
    k_cvt_fcd <<<(NH * DIN) / 1024, 256, 0, stream>>>(fc_D_w, fcb);
    k_dzero   <<<(BL * 32) / 256, 256, 0, stream>>>(Dv, Dd);
    k_conv    <<<dim3(CONV_DIM / 64, L_ / 256, B_), 256, 0, stream>>>(zx, conv_w, conv_b, xs, BCb);
    k_dproj   <<<dim3(BL / 32, 8), 256, 0, stream>>>(xs, fcb, Dd);
    k_chunk   <<<4096, 256, 0, stream>>>(xs, BCb, zx, dt_bias, A_log, y0b, y1b, wo2, dec, scb);
    k_hscan   <<<1024, 256, 0, stream>>>(dec, scb);
    k_inter   <<<4096, 256, 0, stream>>>(BCb, wo2, scb, y0b, y1b);
    k_gate    <<<BL, 256, 0, stream>>>(xs, zx, y0b, y1b, Dd, norm_w, ynb);
    k_gemm_bt <<<dim3(DM / 128, BL / 128), 256, 0, stream>>>(ynb, woutb, BL, DM, DIN, 0, nullptr, DM, (float*)d_out, x);
}